// Round 1
// 8523.206 us; speedup vs baseline: 1.4151x; 1.4151x over previous
//
#include <hip/hip_runtime.h>
#include <hip/hip_bf16.h>

// gNet: 4-layer graph net, B=1, HID=128, N=50000, E=500000.
// Inputs/outputs fp32 (per reference). Internal edge-activations bf16,
// LN stats fp64 via deterministic two-pass reduction.
// R1: scatter-add of edge feats to nodes converted from 128M f32 atomics
//     (75 G atomics/s ceiling, 2.25 GB write traffic) to CSR-based gather
//     (indices are fixed across layers -> build adjacency once per launch).

typedef __hip_bfloat16 bf16;

#define HSTEP 0.1f

__device__ __forceinline__ float b2f(bf16 v){ return __bfloat162float(v); }
__device__ __forceinline__ bf16  f2b(float v){ return __float2bfloat16(v); }
__device__ __forceinline__ unsigned int f2bu(float v){
    return (unsigned int)__builtin_bit_cast(unsigned short, __float2bfloat16(v));
}

// store 8 fp32 as 8 bf16 (one 16B store)
__device__ __forceinline__ void store8(bf16* p, const float* a){
    uint4 q;
    q.x = f2bu(a[0]) | (f2bu(a[1]) << 16);
    q.y = f2bu(a[2]) | (f2bu(a[3]) << 16);
    q.z = f2bu(a[4]) | (f2bu(a[5]) << 16);
    q.w = f2bu(a[6]) | (f2bu(a[7]) << 16);
    *(uint4*)p = q;
}
__device__ __forceinline__ void store8(float* p, const float* a){
    *(float4*)p       = make_float4(a[0],a[1],a[2],a[3]);
    *((float4*)p + 1) = make_float4(a[4],a[5],a[6],a[7]);
}
__device__ __forceinline__ void stor1(bf16* p, float y){ *p = f2b(y); }
__device__ __forceinline__ void stor1(float* p, float y){ *p = y; }

// decode 4 bf16 (8B) -> float4
__device__ __forceinline__ float4 load4bf(const bf16* p){
    uint2 b = *(const uint2*)p;
    float4 q;
    q.x = __uint_as_float(b.x << 16);
    q.y = __uint_as_float(b.x & 0xffff0000u);
    q.z = __uint_as_float(b.y << 16);
    q.w = __uint_as_float(b.y & 0xffff0000u);
    return q;
}

// ---------------- weight prep (fp32 src) ----------------
__global__ void wt_transpose(const float* __restrict__ src, float* __restrict__ dst,
                             int O, int C) {
    int i = blockIdx.x*256 + threadIdx.x;
    if (i >= O*C) return;
    int o = i / C, c = i - o*C;
    dst[c*O + o] = src[i];
}

// KE1 [256][384] -> folded+transposed [256c][256o] (row==col==iInd)
__global__ void wt_ke1eff(const float* __restrict__ src, float* __restrict__ dst) {
    int i = blockIdx.x*256 + threadIdx.x;
    if (i >= 256*256) return;
    int o = i >> 8, c = i & 255;
    float v;
    if (c < 128) v = src[o*384 + c] + src[o*384 + 128 + c];
    else         v = src[o*384 + 128 + c];
    dst[c*256 + o] = v;
}

// ---------------- CSR build (indices fixed -> once per launch) ----------------
__global__ void csr_hist(const int* __restrict__ ind, int* __restrict__ cnt, int E){
    int e = blockIdx.x*256 + threadIdx.x;
    if (e < E) atomicAdd(&cnt[ind[e]], 1);
}

// single-block chunked exclusive scan of cnt[0..Nn) -> rowptr[0..Nn], cursor copy
__global__ void csr_scan(const int* __restrict__ cnt, int* __restrict__ rowptr,
                         int* __restrict__ cursor, int Nn)
{
    __shared__ int part[256];
    int tx = threadIdx.x;
    int chunk = (Nn + 255) / 256;
    int a0 = tx * chunk;
    int a1 = a0 + chunk; if (a1 > Nn) a1 = Nn; if (a0 > Nn) a0 = Nn;
    int s = 0;
    for (int i = a0; i < a1; ++i) s += cnt[i];
    part[tx] = s;
    __syncthreads();
    for (int d = 1; d < 256; d <<= 1) {
        int v = (tx >= d) ? part[tx - d] : 0;
        __syncthreads();
        part[tx] += v;
        __syncthreads();
    }
    int run = (tx == 0) ? 0 : part[tx - 1];
    for (int i = a0; i < a1; ++i) {
        rowptr[i] = run; cursor[i] = run;
        run += cnt[i];
    }
    if (tx == 255) rowptr[Nn] = run;
}

__global__ void csr_fill(const int* __restrict__ ind, int* __restrict__ cursor,
                         int* __restrict__ eadj, int E){
    int e = blockIdx.x*256 + threadIdx.x;
    if (e < E) {
        int p = atomicAdd(&cursor[ind[e]], 1);
        eadj[p] = e;
    }
}

// ---------------- gather: s[:,node] = sum_{e in adj(node)} y[:,e] --------------
// y col-major [E][128]; one wave per node, lane owns channels {2l, 2l+1}.
template<bool YB16>
__launch_bounds__(256)
__global__ void gather_nodes(const void* __restrict__ yv,
                             const int* __restrict__ rowptr,
                             const int* __restrict__ eadj,
                             float* __restrict__ s, int Nn)
{
    int wid  = threadIdx.x >> 6;
    int lane = threadIdx.x & 63;
    int node = blockIdx.x * 4 + wid;
    if (node >= Nn) return;
    int k0 = rowptr[node], k1 = rowptr[node+1];
    float a0 = 0.f, a1 = 0.f;
    for (int k = k0; k < k1; ++k) {
        int e = eadj[k];
        if constexpr (YB16) {
            unsigned int b = *((const unsigned int*)yv + (size_t)e*64 + lane);
            a0 += __uint_as_float(b << 16);
            a1 += __uint_as_float(b & 0xffff0000u);
        } else {
            float2 v = *((const float2*)yv + (size_t)e*64 + lane);
            a0 += v.x; a1 += v.y;
        }
    }
    *(float2*)(s + (size_t)node*128 + lane*2) = make_float2(a0, a1);
}

// ---------------- LN stat reduction (deterministic, no atomics) ----------------
__global__ void ln_reduce(const double* __restrict__ redp, int nb,
                          float* __restrict__ ln, double cnt)
{
    __shared__ double s0[256], s1[256];
    int tx = threadIdx.x;
    double a = 0.0, b = 0.0;
    for (int i = tx; i < nb; i += 256) { a += redp[2*i]; b += redp[2*i+1]; }
    s0[tx] = a; s1[tx] = b;
    __syncthreads();
    for (int s = 128; s > 0; s >>= 1) {
        if (tx < s) { s0[tx] += s0[tx+s]; s1[tx] += s1[tx+s]; }
        __syncthreads();
    }
    if (tx == 0) {
        double m = s0[0] / cnt;
        double var = s1[0] / cnt - m*m;
        if (var < 0.0) var = 0.0;
        ln[0] = (float)m;
        ln[1] = (float)(1.0 / sqrt(var + 1e-5));
    }
}

// ---------------- GEMM1: u = W1 @ v, + per-block sum/sumsq partials ----------------
enum { M1_OPEN = 0, M1_EDGE = 1, M1_NODE = 2 };

template<int OC, int IC, int MODE, typename OUT_T>
__launch_bounds__(256)
__global__ void mm1_kernel(const float* __restrict__ Wt,     // [IC][OC] fp32
                           const float* __restrict__ xin,    // OPEN: [IC][n] fp32 row-major
                           const float* __restrict__ xn_cm,  // [N][128] col-major
                           const float* __restrict__ xe_rm,  // [128][E] row-major
                           const float* __restrict__ si,     // [N][128] col-major
                           const float* __restrict__ sj,     // [N][128] col-major
                           const int*   __restrict__ iInd,
                           OUT_T* __restrict__ uout,         // [OC][n] row-major
                           int n, double* __restrict__ redp)
{
    constexpr int RPT = OC/32;
    constexpr int KC = 32, TN = 64;
    __shared__ float lv[KC][TN];
    __shared__ int lidx[TN];
    __shared__ double sred[512];
    const int tx = threadIdx.x;
    const int tr = tx & 31, tc = tx >> 5;
    const int x0 = blockIdx.x * TN;

    if constexpr (MODE == M1_EDGE) {
        if (tx < TN) lidx[tx] = (x0 + tx < n) ? iInd[x0 + tx] : 0;
    }
    __syncthreads();

    float acc[RPT][8];
    #pragma unroll
    for (int ri=0; ri<RPT; ++ri)
        #pragma unroll
        for (int ei=0; ei<8; ++ei) acc[ri][ei] = 0.f;

    for (int c0 = 0; c0 < IC; c0 += KC) {
        if constexpr (MODE == M1_OPEN) {
            // fp32 row-major [IC][n], float4 along x
            #pragma unroll
            for (int k=0; k<2; ++k) {
                int id = k*256 + tx;
                int xq = id & 15, cc = id >> 4;
                int x = x0 + xq*4;
                const float* p = xin + (size_t)(c0+cc)*n + x;
                float4 q;
                if (x + 3 < n) q = *(const float4*)p;
                else {
                    q.x = (x  <n)?p[0]:0.f; q.y = (x+1<n)?p[1]:0.f;
                    q.z = (x+2<n)?p[2]:0.f; q.w = (x+3<n)?p[3]:0.f;
                }
                *(float4*)&lv[cc][xq*4] = q;
            }
        } else if constexpr (MODE == M1_EDGE) {
            if (c0 < 128) {   // gathered node features (col-major, float4)
                #pragma unroll
                for (int k=0; k<2; ++k) {
                    int id = k*256 + tx;
                    int xx = id & 63, cg = id >> 6;
                    const float* p = xn_cm + (size_t)lidx[xx]*128 + c0 + cg*4;
                    float4 q = *(const float4*)p;
                    lv[cg*4+0][xx] = q.x; lv[cg*4+1][xx] = q.y;
                    lv[cg*4+2][xx] = q.z; lv[cg*4+3][xx] = q.w;
                }
            } else {          // edge features (row-major, float4 along x)
                #pragma unroll
                for (int k=0; k<2; ++k) {
                    int id = k*256 + tx;
                    int xq = id & 15, cc = id >> 4;
                    int x = x0 + xq*4;
                    const float* p = xe_rm + (size_t)(c0-128+cc)*n + x;
                    float4 q;
                    if (x + 3 < n) q = *(const float4*)p;
                    else {
                        q.x = (x  <n)?p[0]:0.f; q.y = (x+1<n)?p[1]:0.f;
                        q.z = (x+2<n)?p[2]:0.f; q.w = (x+3<n)?p[3]:0.f;
                    }
                    *(float4*)&lv[cc][xq*4] = q;
                }
            }
        } else {              // M1_NODE: [0.5*(si+sj); si-sj; xn] col-major
            #pragma unroll
            for (int k=0; k<2; ++k) {
                int id = k*256 + tx;
                int xx = id & 63, cg = id >> 6;
                int x = x0 + xx;
                int c = c0 + cg*4;
                float4 q;
                if (x < n) {
                    if (c0 < 128) {
                        float4 a = *(const float4*)(si + (size_t)x*128 + c);
                        float4 b = *(const float4*)(sj + (size_t)x*128 + c);
                        q.x = 0.5f*(a.x+b.x); q.y = 0.5f*(a.y+b.y);
                        q.z = 0.5f*(a.z+b.z); q.w = 0.5f*(a.w+b.w);
                    } else if (c0 < 256) {
                        float4 a = *(const float4*)(si + (size_t)x*128 + (c-128));
                        float4 b = *(const float4*)(sj + (size_t)x*128 + (c-128));
                        q.x = a.x-b.x; q.y = a.y-b.y; q.z = a.z-b.z; q.w = a.w-b.w;
                    } else {
                        q = *(const float4*)(xn_cm + (size_t)x*128 + (c-256));
                    }
                } else { q.x=q.y=q.z=q.w=0.f; }
                lv[cg*4+0][xx]=q.x; lv[cg*4+1][xx]=q.y;
                lv[cg*4+2][xx]=q.z; lv[cg*4+3][xx]=q.w;
            }
        }
        __syncthreads();
        for (int cc=0; cc<KC; ++cc) {
            const float* wrow = Wt + (size_t)(c0+cc)*OC + tr*RPT;
            float w[RPT];
            #pragma unroll
            for (int ri=0; ri<RPT; ++ri) w[ri] = wrow[ri];
            float vv[8];
            #pragma unroll
            for (int ei=0; ei<8; ++ei) vv[ei] = lv[cc][tc*8+ei];
            #pragma unroll
            for (int ri=0; ri<RPT; ++ri)
                #pragma unroll
                for (int ei=0; ei<8; ++ei)
                    acc[ri][ei] = fmaf(w[ri], vv[ei], acc[ri][ei]);
        }
        __syncthreads();
    }

    // ---- store u + per-block fp64 partial ----
    double ls = 0.0, ls2 = 0.0;
    const bool full = (x0 + TN <= n);
    if (full) {
        #pragma unroll
        for (int ri=0; ri<RPT; ++ri) {
            int r = tr*RPT + ri;
            store8(uout + (size_t)r*n + x0 + tc*8, acc[ri]);
            #pragma unroll
            for (int ei=0; ei<8; ++ei){ double y = acc[ri][ei]; ls += y; ls2 += y*y; }
        }
    } else {
        #pragma unroll
        for (int ri=0; ri<RPT; ++ri) {
            int r = tr*RPT + ri;
            #pragma unroll
            for (int ei=0; ei<8; ++ei) {
                int x = x0 + tc*8 + ei;
                if (x < n) {
                    float y = acc[ri][ei];
                    stor1(uout + (size_t)r*n + x, y);
                    ls += y; ls2 += (double)y*y;
                }
            }
        }
    }
    sred[tx] = ls; sred[256+tx] = ls2;
    __syncthreads();
    for (int s=128; s>0; s>>=1) {
        if (tx < s) { sred[tx] += sred[tx+s]; sred[256+tx] += sred[256+tx+s]; }
        __syncthreads();
    }
    if (tx == 0) {
        redp[2*(size_t)blockIdx.x]     = sred[0];
        redp[2*(size_t)blockIdx.x + 1] = sred[256];
    }
}

// ---------------- GEMM2: y = W2 @ relu((u-m)*rstd), fused epilogues ----------------
enum { IN_RM_BF16 = 0, IN_RM_F32 = 1, IN_CM_F32 = 2 };
enum { EPI_STORE_CM = 0, EPI_STORE_RM = 1, EPI_EDGE = 2, EPI_NODE = 3, EPI_OUT = 4,
       EPI_EDGE_Y = 5 };

template<int OC, int IC, int INMODE, int EPI, bool LNRELU, bool YB16 = false>
__launch_bounds__(256)
__global__ void mm2_kernel(const float* __restrict__ Wt,     // [IC][OC] fp32
                           const void*  __restrict__ uin,
                           const float* __restrict__ ln,     // {mean, rstd}
                           const int* __restrict__ iInd, const int* __restrict__ jInd,
                           float* __restrict__ dstA,         // xe_rm / xn_cm
                           float* __restrict__ si, float* __restrict__ sj,
                           float* __restrict__ outb,         // fp32 out (EPI_OUT)
                           int n)
{
    constexpr int RPT = OC/32;
    constexpr int KC = 32, TN = 64;
    __shared__ float lv[KC][TN];
    __shared__ int lidxI[TN], lidxJ[TN];
    const int tx = threadIdx.x;
    const int tr = tx & 31, tc = tx >> 5;
    const int x0 = blockIdx.x * TN;

    if constexpr (EPI == EPI_EDGE) {
        if (tx < TN) {
            int x = x0 + tx;
            lidxI[tx] = (x < n) ? iInd[x] : 0;
            lidxJ[tx] = (x < n) ? jInd[x] : 0;
        }
    }
    __syncthreads();

    float mean = 0.f, rstd = 1.f;
    if constexpr (LNRELU) { mean = ln[0]; rstd = ln[1]; }

    float acc[RPT][8];
    #pragma unroll
    for (int ri=0; ri<RPT; ++ri)
        #pragma unroll
        for (int ei=0; ei<8; ++ei) acc[ri][ei] = 0.f;

    for (int c0 = 0; c0 < IC; c0 += KC) {
        if constexpr (INMODE == IN_CM_F32) {
            #pragma unroll
            for (int k=0; k<2; ++k) {
                int id = k*256 + tx;
                int xx = id & 63, cg = id >> 6;
                int x = x0 + xx;
                float4 q;
                if (x < n) q = *(const float4*)((const float*)uin + (size_t)x*128 + c0 + cg*4);
                else { q.x=q.y=q.z=q.w=0.f; }
                if constexpr (LNRELU) {
                    q.x = fmaxf(0.f,(q.x-mean)*rstd); q.y = fmaxf(0.f,(q.y-mean)*rstd);
                    q.z = fmaxf(0.f,(q.z-mean)*rstd); q.w = fmaxf(0.f,(q.w-mean)*rstd);
                }
                lv[cg*4+0][xx]=q.x; lv[cg*4+1][xx]=q.y;
                lv[cg*4+2][xx]=q.z; lv[cg*4+3][xx]=q.w;
            }
        } else {
            #pragma unroll
            for (int k=0; k<2; ++k) {
                int id = k*256 + tx;
                int xq = id & 15, cc = id >> 4;
                int x = x0 + xq*4;
                int c = c0 + cc;
                float4 q;
                if constexpr (INMODE == IN_RM_F32) {
                    const float* p = (const float*)uin + (size_t)c*n + x;
                    if (x + 3 < n) q = *(const float4*)p;
                    else {
                        q.x = (x  <n)?p[0]:0.f; q.y = (x+1<n)?p[1]:0.f;
                        q.z = (x+2<n)?p[2]:0.f; q.w = (x+3<n)?p[3]:0.f;
                    }
                } else {
                    const bf16* p = (const bf16*)uin + (size_t)c*n + x;
                    if (x + 3 < n) q = load4bf(p);
                    else {
                        q.x = (x  <n)?b2f(p[0]):0.f; q.y = (x+1<n)?b2f(p[1]):0.f;
                        q.z = (x+2<n)?b2f(p[2]):0.f; q.w = (x+3<n)?b2f(p[3]):0.f;
                    }
                }
                if constexpr (LNRELU) {
                    q.x = fmaxf(0.f,(q.x-mean)*rstd); q.y = fmaxf(0.f,(q.y-mean)*rstd);
                    q.z = fmaxf(0.f,(q.z-mean)*rstd); q.w = fmaxf(0.f,(q.w-mean)*rstd);
                }
                *(float4*)&lv[cc][xq*4] = q;
            }
        }
        __syncthreads();
        for (int cc=0; cc<KC; ++cc) {
            const float* wrow = Wt + (size_t)(c0+cc)*OC + tr*RPT;
            float w[RPT];
            #pragma unroll
            for (int ri=0; ri<RPT; ++ri) w[ri] = wrow[ri];
            float vv[8];
            #pragma unroll
            for (int ei=0; ei<8; ++ei) vv[ei] = lv[cc][tc*8+ei];
            #pragma unroll
            for (int ri=0; ri<RPT; ++ri)
                #pragma unroll
                for (int ei=0; ei<8; ++ei)
                    acc[ri][ei] = fmaf(w[ri], vv[ei], acc[ri][ei]);
        }
        __syncthreads();
    }

    const bool full = (x0 + TN <= n);
    if constexpr (EPI == EPI_STORE_CM) {           // xn col-major, RPT==4
        #pragma unroll
        for (int ei=0; ei<8; ++ei) {
            int x = x0 + tc*8 + ei;
            if (x < n) {
                float4 q = make_float4(acc[0][ei],acc[1][ei],acc[2][ei],acc[3][ei]);
                *(float4*)(dstA + (size_t)x*128 + tr*4) = q;
            }
        }
    } else if constexpr (EPI == EPI_STORE_RM) {    // xe row-major
        if (full) {
            #pragma unroll
            for (int ri=0; ri<RPT; ++ri)
                store8(dstA + (size_t)(tr*RPT+ri)*n + x0 + tc*8, acc[ri]);
        } else {
            #pragma unroll
            for (int ri=0; ri<RPT; ++ri)
                #pragma unroll
                for (int ei=0; ei<8; ++ei) {
                    int x = x0 + tc*8 + ei;
                    if (x < n) dstA[(size_t)(tr*RPT+ri)*n + x] = acc[ri][ei];
                }
        }
    } else if constexpr (EPI == EPI_EDGE) {        // xe += h*y, scatter-add si/sj (fallback)
        #pragma unroll
        for (int ri=0; ri<RPT; ++ri) {
            int r = tr*RPT + ri;
            if (full) {
                float* p = dstA + (size_t)r*n + x0 + tc*8;
                float4 a = *(float4*)p, b = *((float4*)p + 1);
                a.x += HSTEP*acc[ri][0]; a.y += HSTEP*acc[ri][1];
                a.z += HSTEP*acc[ri][2]; a.w += HSTEP*acc[ri][3];
                b.x += HSTEP*acc[ri][4]; b.y += HSTEP*acc[ri][5];
                b.z += HSTEP*acc[ri][6]; b.w += HSTEP*acc[ri][7];
                *(float4*)p = a; *((float4*)p + 1) = b;
            } else {
                #pragma unroll
                for (int ei=0; ei<8; ++ei) {
                    int x = x0 + tc*8 + ei;
                    if (x < n) dstA[(size_t)r*n + x] += HSTEP*acc[ri][ei];
                }
            }
            #pragma unroll
            for (int ei=0; ei<8; ++ei) {
                int xx = tc*8 + ei, x = x0 + xx;
                if (x < n) {
                    float y = acc[ri][ei];
                    unsafeAtomicAdd(si + (size_t)lidxI[xx]*128 + r, y);
                    unsafeAtomicAdd(sj + (size_t)lidxJ[xx]*128 + r, y);
                }
            }
        }
    } else if constexpr (EPI == EPI_EDGE_Y) {      // xe += h*y, store y col-major [E][128]
        #pragma unroll
        for (int ri=0; ri<RPT; ++ri) {
            int r = tr*RPT + ri;
            if (full) {
                float* p = dstA + (size_t)r*n + x0 + tc*8;
                float4 a = *(float4*)p, b = *((float4*)p + 1);
                a.x += HSTEP*acc[ri][0]; a.y += HSTEP*acc[ri][1];
                a.z += HSTEP*acc[ri][2]; a.w += HSTEP*acc[ri][3];
                b.x += HSTEP*acc[ri][4]; b.y += HSTEP*acc[ri][5];
                b.z += HSTEP*acc[ri][6]; b.w += HSTEP*acc[ri][7];
                *(float4*)p = a; *((float4*)p + 1) = b;
            } else {
                #pragma unroll
                for (int ei=0; ei<8; ++ei) {
                    int x = x0 + tc*8 + ei;
                    if (x < n) dstA[(size_t)r*n + x] += HSTEP*acc[ri][ei];
                }
            }
        }
        #pragma unroll
        for (int ei=0; ei<8; ++ei) {               // RPT==4 here (OC=128)
            int x = x0 + tc*8 + ei;
            if (x < n) {
                if constexpr (YB16) {
                    uint2 q;
                    q.x = f2bu(acc[0][ei]) | (f2bu(acc[1][ei]) << 16);
                    q.y = f2bu(acc[2][ei]) | (f2bu(acc[3][ei]) << 16);
                    *(uint2*)((bf16*)si + (size_t)x*128 + tr*4) = q;
                } else {
                    *(float4*)(si + (size_t)x*128 + tr*4) =
                        make_float4(acc[0][ei],acc[1][ei],acc[2][ei],acc[3][ei]);
                }
            }
        }
    } else if constexpr (EPI == EPI_NODE) {        // xn += h*y (col-major, RPT==4)
        #pragma unroll
        for (int ei=0; ei<8; ++ei) {
            int x = x0 + tc*8 + ei;
            if (x < n) {
                float* p = dstA + (size_t)x*128 + tr*4;
                float4 q = *(float4*)p;
                q.x += HSTEP*acc[0][ei]; q.y += HSTEP*acc[1][ei];
                q.z += HSTEP*acc[2][ei]; q.w += HSTEP*acc[3][ei];
                *(float4*)p = q;
            }
        }
    } else {                                       // EPI_OUT: fp32 row-major
        #pragma unroll
        for (int ri=0; ri<RPT; ++ri) {
            int r = tr*RPT + ri;
            if (full) {
                store8(outb + (size_t)r*n + x0 + tc*8, acc[ri]);
            } else {
                #pragma unroll
                for (int ei=0; ei<8; ++ei) {
                    int x = x0 + tc*8 + ei;
                    if (x < n) outb[(size_t)r*n + x] = acc[ri][ei];
                }
            }
        }
    }
}

extern "C" void kernel_launch(void* const* d_in, const int* in_sizes, int n_in,
                              void* d_out, int out_size, void* d_ws, size_t ws_size,
                              hipStream_t stream)
{
    const int N = in_sizes[0] / 32;          // 50000
    const int E = in_sizes[1] / 32;          // 500000
    const int NL = in_sizes[9] / (256*384);  // 4

    const float* xn_in = (const float*)d_in[0];
    const float* xe_in = (const float*)d_in[1];
    const int*   iInd  = (const int*)d_in[2];
    const int*   jInd  = (const int*)d_in[3];
    const float* K1N = (const float*)d_in[4];
    const float* K2N = (const float*)d_in[5];
    const float* K1E = (const float*)d_in[6];
    const float* K2E = (const float*)d_in[7];
    const float* KNo = (const float*)d_in[8];
    const float* KE1 = (const float*)d_in[9];
    const float* KE2 = (const float*)d_in[10];
    const float* KN1 = (const float*)d_in[11];
    const float* KN2 = (const float*)d_in[12];

    char* base = (char*)d_ws;
    size_t off = 0;
    auto carve = [&](size_t bytes)->void* {
        void* p = base + off; off += (bytes + 255) & ~(size_t)255; return p;
    };
    float* xn = (float*)carve((size_t)128*N*sizeof(float));   // col-major [N][128]
    float* xe = (float*)carve((size_t)128*E*sizeof(float));   // row-major [128][E]
    bf16*  u  = (bf16*) carve((size_t)256*E*sizeof(bf16));    // row-major [256][E]
    float* un = (float*)u;                                    // alias: node u [256][N] f32
    float* si = (float*)carve((size_t)128*N*sizeof(float));   // col-major
    float* sj = (float*)carve((size_t)128*N*sizeof(float));   // col-major
    float* wts= (float*)carve(300000*sizeof(float));
    double* redp = (double*)carve(2*8192*sizeof(double));     // per-block LN partials
    float* lnp = (float*)carve(256);
    // CSR adjacency (indices fixed across layers)
    int* cnt      = (int*)carve((size_t)N*sizeof(int));
    int* rowptr_i = (int*)carve((size_t)(N+1)*sizeof(int));
    int* rowptr_j = (int*)carve((size_t)(N+1)*sizeof(int));
    int* cur_i    = (int*)carve((size_t)N*sizeof(int));
    int* cur_j    = (int*)carve((size_t)N*sizeof(int));
    int* eadj_i   = (int*)carve((size_t)E*sizeof(int));
    int* eadj_j   = (int*)carve((size_t)E*sizeof(int));

    if (ws_size < off) return;

    // y buffer: col-major [E][128]; prefer fp32, fall back bf16, else atomics.
    int ymode = 0;                       // 0 = atomic fallback, 1 = bf16 y, 2 = f32 y
    void* y = nullptr;
    if (off + (size_t)128*E*sizeof(float) <= ws_size) { y = base + off; ymode = 2; }
    else if (off + (size_t)128*E*sizeof(bf16) <= ws_size) { y = base + off; ymode = 1; }

    float* K1Nt = wts;                 // [32][128]
    float* K2Nt = K1Nt + 32*128;       // [128][128]
    float* K1Et = K2Nt + 128*128;      // [32][128]
    float* K2Et = K1Et + 32*128;       // [128][128]
    float* KNoT = K2Et + 128*128;      // [128][64]
    float* KE1t = KNoT + 128*64;       // [256][256]
    float* KE2t = KE1t + 256*256;      // [256][128]
    float* KN1t = KE2t + 256*128;      // [384][256]
    float* KN2t = KN1t + 384*256;      // [256][128]

    wt_transpose<<<dim3((128*32 +255)/256),dim3(256),0,stream>>>(K1N, K1Nt, 128, 32);
    wt_transpose<<<dim3((128*128+255)/256),dim3(256),0,stream>>>(K2N, K2Nt, 128, 128);
    wt_transpose<<<dim3((128*32 +255)/256),dim3(256),0,stream>>>(K1E, K1Et, 128, 32);
    wt_transpose<<<dim3((128*128+255)/256),dim3(256),0,stream>>>(K2E, K2Et, 128, 128);
    wt_transpose<<<dim3((64*128 +255)/256),dim3(256),0,stream>>>(KNo, KNoT, 64, 128);

    const int gN = (N + 63)/64, gE = (E + 63)/64;
    const int gEb = (E + 255)/256;

    if (ymode) {    // build CSR once (hist -> scan -> fill)
        (void)hipMemsetAsync(cnt, 0, (size_t)N*sizeof(int), stream);
        csr_hist<<<gEb,256,0,stream>>>(iInd, cnt, E);
        csr_scan<<<1,256,0,stream>>>(cnt, rowptr_i, cur_i, N);
        csr_fill<<<gEb,256,0,stream>>>(iInd, cur_i, eadj_i, E);
        (void)hipMemsetAsync(cnt, 0, (size_t)N*sizeof(int), stream);
        csr_hist<<<gEb,256,0,stream>>>(jInd, cnt, E);
        csr_scan<<<1,256,0,stream>>>(cnt, rowptr_j, cur_j, N);
        csr_fill<<<gEb,256,0,stream>>>(jInd, cur_j, eadj_j, E);
    }

    // ---- opening: nodes ----
    mm1_kernel<128,32,M1_OPEN,bf16><<<gN,256,0,stream>>>(
        K1Nt, xn_in, nullptr, nullptr, nullptr, nullptr, nullptr, u, N, redp);
    ln_reduce<<<1,256,0,stream>>>(redp, gN, lnp, 128.0*N);
    mm2_kernel<128,128,IN_RM_BF16,EPI_STORE_CM,true><<<gN,256,0,stream>>>(
        K2Nt, u, lnp, nullptr, nullptr, xn, nullptr, nullptr, nullptr, N);

    // ---- opening: edges ----
    mm1_kernel<128,32,M1_OPEN,bf16><<<gE,256,0,stream>>>(
        K1Et, xe_in, nullptr, nullptr, nullptr, nullptr, nullptr, u, E, redp);
    ln_reduce<<<1,256,0,stream>>>(redp, gE, lnp, 128.0*E);
    mm2_kernel<128,128,IN_RM_BF16,EPI_STORE_RM,true><<<gE,256,0,stream>>>(
        K2Et, u, lnp, nullptr, nullptr, xe, nullptr, nullptr, nullptr, E);

    for (int l = 0; l < NL; ++l) {
        wt_ke1eff<<<dim3(256),dim3(256),0,stream>>>(KE1 + (size_t)l*256*384, KE1t);
        wt_transpose<<<dim3((128*256+255)/256),dim3(256),0,stream>>>(KE2 + (size_t)l*128*256, KE2t, 128, 256);
        wt_transpose<<<dim3((256*384+255)/256),dim3(256),0,stream>>>(KN1 + (size_t)l*256*384, KN1t, 256, 384);
        wt_transpose<<<dim3((128*256+255)/256),dim3(256),0,stream>>>(KN2 + (size_t)l*128*256, KN2t, 128, 256);

        // edge double_layer
        mm1_kernel<256,256,M1_EDGE,bf16><<<gE,256,0,stream>>>(
            KE1t, nullptr, xn, xe, nullptr, nullptr, iInd, u, E, redp);
        ln_reduce<<<1,256,0,stream>>>(redp, gE, lnp, 256.0*E);

        if (ymode == 2) {
            mm2_kernel<128,256,IN_RM_BF16,EPI_EDGE_Y,true,false><<<gE,256,0,stream>>>(
                KE2t, u, lnp, nullptr, nullptr, xe, (float*)y, nullptr, nullptr, E);
            gather_nodes<false><<<(N+3)/4,256,0,stream>>>(y, rowptr_i, eadj_i, si, N);
            gather_nodes<false><<<(N+3)/4,256,0,stream>>>(y, rowptr_j, eadj_j, sj, N);
        } else if (ymode == 1) {
            mm2_kernel<128,256,IN_RM_BF16,EPI_EDGE_Y,true,true><<<gE,256,0,stream>>>(
                KE2t, u, lnp, nullptr, nullptr, xe, (float*)y, nullptr, nullptr, E);
            gather_nodes<true><<<(N+3)/4,256,0,stream>>>(y, rowptr_i, eadj_i, si, N);
            gather_nodes<true><<<(N+3)/4,256,0,stream>>>(y, rowptr_j, eadj_j, sj, N);
        } else {
            (void)hipMemsetAsync(si, 0, (size_t)128*N*sizeof(float), stream);
            (void)hipMemsetAsync(sj, 0, (size_t)128*N*sizeof(float), stream);
            mm2_kernel<128,256,IN_RM_BF16,EPI_EDGE,true><<<gE,256,0,stream>>>(
                KE2t, u, lnp, iInd, jInd, xe, si, sj, nullptr, E);
        }

        // node double_layer
        mm1_kernel<256,384,M1_NODE,float><<<gN,256,0,stream>>>(
            KN1t, nullptr, xn, nullptr, si, sj, nullptr, un, N, redp);
        ln_reduce<<<1,256,0,stream>>>(redp, gN, lnp, 256.0*N);
        mm2_kernel<128,256,IN_RM_F32,EPI_NODE,true><<<gN,256,0,stream>>>(
            KN2t, un, lnp, nullptr, nullptr, xn, nullptr, nullptr, nullptr, N);
    }

    // ---- final: xn_out = KNout @ xn ; copy xe (already fp32 row-major) ----
    mm2_kernel<64,128,IN_CM_F32,EPI_OUT,false><<<gN,256,0,stream>>>(
        KNoT, xn, nullptr, nullptr, nullptr, nullptr, nullptr, nullptr, (float*)d_out, N);
    (void)hipMemcpyAsync((float*)d_out + (size_t)64*N, xe,
                         (size_t)128*E*sizeof(float), hipMemcpyDeviceToDevice, stream);
}

// Round 2
// 5252.083 us; speedup vs baseline: 2.2964x; 1.6228x over previous
//
#include <hip/hip_runtime.h>
#include <hip/hip_bf16.h>

// gNet: 4-layer graph net, B=1, HID=128, N=50000, E=500000.
// R1: scatter->CSR gather (atomics removed).
// R2: edge-side GEMMs (256x256xE and 128x256xE) moved from VALU f32 to
//     MFMA bf16 (mfma_f32_16x16x32_bf16). u col-major [E][256] bf16,
//     xe master col-major [E][128] f32 (+final transpose), xn bf16 shadow
//     for the per-edge gather. LDS B-tile XOR-swizzled (G4).

typedef __hip_bfloat16 bf16;
typedef __attribute__((ext_vector_type(8))) short bf16x8;
typedef __attribute__((ext_vector_type(4))) float f32x4;

#define HSTEP 0.1f

__device__ __forceinline__ float b2f(bf16 v){ return __bfloat162float(v); }
__device__ __forceinline__ bf16  f2b(float v){ return __float2bfloat16(v); }
__device__ __forceinline__ unsigned int f2bu(float v){
    return (unsigned int)__builtin_bit_cast(unsigned short, __float2bfloat16(v));
}

// store 8 fp32 as 8 bf16 (one 16B store)
__device__ __forceinline__ void store8(bf16* p, const float* a){
    uint4 q;
    q.x = f2bu(a[0]) | (f2bu(a[1]) << 16);
    q.y = f2bu(a[2]) | (f2bu(a[3]) << 16);
    q.z = f2bu(a[4]) | (f2bu(a[5]) << 16);
    q.w = f2bu(a[6]) | (f2bu(a[7]) << 16);
    *(uint4*)p = q;
}
__device__ __forceinline__ void store8(float* p, const float* a){
    *(float4*)p       = make_float4(a[0],a[1],a[2],a[3]);
    *((float4*)p + 1) = make_float4(a[4],a[5],a[6],a[7]);
}
__device__ __forceinline__ void stor1(bf16* p, float y){ *p = f2b(y); }
__device__ __forceinline__ void stor1(float* p, float y){ *p = y; }

// decode 4 bf16 (8B) -> float4
__device__ __forceinline__ float4 load4bf(const bf16* p){
    uint2 b = *(const uint2*)p;
    float4 q;
    q.x = __uint_as_float(b.x << 16);
    q.y = __uint_as_float(b.x & 0xffff0000u);
    q.z = __uint_as_float(b.y << 16);
    q.w = __uint_as_float(b.y & 0xffff0000u);
    return q;
}

// ---------------- weight prep ----------------
__global__ void wt_transpose(const float* __restrict__ src, float* __restrict__ dst,
                             int O, int C) {
    int i = blockIdx.x*256 + threadIdx.x;
    if (i >= O*C) return;
    int o = i / C, c = i - o*C;
    dst[c*O + o] = src[i];
}

// KE1 [256][384] -> folded bf16 [256 o][256 c] (row==col==iInd), k-contiguous
__global__ void wt_ke1_bf(const float* __restrict__ src, bf16* __restrict__ dst) {
    int i = blockIdx.x*256 + threadIdx.x;
    if (i >= 256*256) return;
    int o = i >> 8, c = i & 255;
    float v;
    if (c < 128) v = src[o*384 + c] + src[o*384 + 128 + c];
    else         v = src[o*384 + 128 + c];
    dst[i] = f2b(v);
}

// elementwise f32 -> bf16 (KE2: [128][256] row-major, already k-contiguous)
__global__ void wt_cast_bf(const float* __restrict__ src, bf16* __restrict__ dst, int cnt) {
    int i = blockIdx.x*256 + threadIdx.x;
    if (i < cnt) dst[i] = f2b(src[i]);
}

// ---------------- CSR build (indices fixed -> once per launch) ----------------
__global__ void csr_hist(const int* __restrict__ ind, int* __restrict__ cnt, int E){
    int e = blockIdx.x*256 + threadIdx.x;
    if (e < E) atomicAdd(&cnt[ind[e]], 1);
}

__global__ void csr_scan(const int* __restrict__ cnt, int* __restrict__ rowptr,
                         int* __restrict__ cursor, int Nn)
{
    __shared__ int part[256];
    int tx = threadIdx.x;
    int chunk = (Nn + 255) / 256;
    int a0 = tx * chunk;
    int a1 = a0 + chunk; if (a1 > Nn) a1 = Nn; if (a0 > Nn) a0 = Nn;
    int s = 0;
    for (int i = a0; i < a1; ++i) s += cnt[i];
    part[tx] = s;
    __syncthreads();
    for (int d = 1; d < 256; d <<= 1) {
        int v = (tx >= d) ? part[tx - d] : 0;
        __syncthreads();
        part[tx] += v;
        __syncthreads();
    }
    int run = (tx == 0) ? 0 : part[tx - 1];
    for (int i = a0; i < a1; ++i) {
        rowptr[i] = run; cursor[i] = run;
        run += cnt[i];
    }
    if (tx == 255) rowptr[Nn] = run;
}

__global__ void csr_fill(const int* __restrict__ ind, int* __restrict__ cursor,
                         int* __restrict__ eadj, int E){
    int e = blockIdx.x*256 + threadIdx.x;
    if (e < E) {
        int p = atomicAdd(&cursor[ind[e]], 1);
        eadj[p] = e;
    }
}

// ---------------- gather: s[:,node] = sum_{e in adj(node)} y[:,e] --------------
template<bool YB16>
__launch_bounds__(256)
__global__ void gather_nodes(const void* __restrict__ yv,
                             const int* __restrict__ rowptr,
                             const int* __restrict__ eadj,
                             float* __restrict__ s, int Nn)
{
    int wid  = threadIdx.x >> 6;
    int lane = threadIdx.x & 63;
    int node = blockIdx.x * 4 + wid;
    if (node >= Nn) return;
    int k0 = rowptr[node], k1 = rowptr[node+1];
    float a0 = 0.f, a1 = 0.f;
    for (int k = k0; k < k1; ++k) {
        int e = eadj[k];
        if constexpr (YB16) {
            unsigned int b = *((const unsigned int*)yv + (size_t)e*64 + lane);
            a0 += __uint_as_float(b << 16);
            a1 += __uint_as_float(b & 0xffff0000u);
        } else {
            float2 v = *((const float2*)yv + (size_t)e*64 + lane);
            a0 += v.x; a1 += v.y;
        }
    }
    *(float2*)(s + (size_t)node*128 + lane*2) = make_float2(a0, a1);
}

// ---------------- LN stat reduction (deterministic) ----------------
__global__ void ln_reduce(const double* __restrict__ redp, int nb,
                          float* __restrict__ ln, double cnt)
{
    __shared__ double s0[256], s1[256];
    int tx = threadIdx.x;
    double a = 0.0, b = 0.0;
    for (int i = tx; i < nb; i += 256) { a += redp[2*i]; b += redp[2*i+1]; }
    s0[tx] = a; s1[tx] = b;
    __syncthreads();
    for (int s = 128; s > 0; s >>= 1) {
        if (tx < s) { s0[tx] += s0[tx+s]; s1[tx] += s1[tx+s]; }
        __syncthreads();
    }
    if (tx == 0) {
        double m = s0[0] / cnt;
        double var = s1[0] / cnt - m*m;
        if (var < 0.0) var = 0.0;
        ln[0] = (float)m;
        ln[1] = (float)(1.0 / sqrt(var + 1e-5));
    }
}

// ============ MFMA edge GEMM1: u[256][E] = W1[256x256] @ V, V=[xn(iInd);xe] ======
// u stored col-major [E][256] bf16. LDS B-tile [64 e][256 k] bf16, XOR swizzle.
__launch_bounds__(256)
__global__ void mfma_mm1_edge(const bf16* __restrict__ Wb,   // [256 o][256 k]
                              const bf16* __restrict__ xnb,  // [N][128] bf16
                              const float* __restrict__ xe,  // [E][128] f32 col-major
                              const int* __restrict__ iInd,
                              bf16* __restrict__ ucm,        // [E][256] bf16
                              int E, double* __restrict__ redp)
{
    __shared__ __align__(16) unsigned short Vs[64*256];
    __shared__ double sred[512];
    const int tx = threadIdx.x;
    const int x0 = blockIdx.x * 64;
    const int es = tx & 63, cg = tx >> 6;
    const int xedge = x0 + es;
    const bool ev = xedge < E;
    const int gidx = ev ? iInd[xedge] : 0;
    const unsigned swz = (unsigned)((es & 7) << 3);

    // stage node part k=0..127 (bf16 gather)
    #pragma unroll
    for (int p = 0; p < 4; ++p) {
        int k0 = p*32 + cg*8;
        uint4 q = make_uint4(0,0,0,0);
        if (ev) q = *(const uint4*)(xnb + (size_t)gidx*128 + k0);
        *(uint4*)&Vs[(unsigned)(es*256 + k0) ^ swz] = q;
    }
    // stage edge part k=128..255 (f32 col-major -> bf16)
    #pragma unroll
    for (int p = 0; p < 4; ++p) {
        int k0 = 128 + p*32 + cg*8;
        uint4 q = make_uint4(0,0,0,0);
        if (ev) {
            const float* s = xe + (size_t)xedge*128 + (k0 - 128);
            float4 a = *(const float4*)s, b = *(const float4*)(s + 4);
            q.x = f2bu(a.x) | (f2bu(a.y) << 16);
            q.y = f2bu(a.z) | (f2bu(a.w) << 16);
            q.z = f2bu(b.x) | (f2bu(b.y) << 16);
            q.w = f2bu(b.z) | (f2bu(b.w) << 16);
        }
        *(uint4*)&Vs[(unsigned)(es*256 + k0) ^ swz] = q;
    }
    __syncthreads();

    const int w = tx >> 6, l = tx & 63;
    const int colb = l & 15, grp = l >> 4;
    f32x4 acc[4][4];
    #pragma unroll
    for (int m=0;m<4;++m)
        #pragma unroll
        for (int n=0;n<4;++n) acc[m][n] = (f32x4){0.f,0.f,0.f,0.f};

    #pragma unroll
    for (int kc = 0; kc < 8; ++kc) {
        const int kf = kc*32 + grp*8;
        bf16x8 a[4], b[4];
        #pragma unroll
        for (int m=0;m<4;++m) {
            int row = w*64 + m*16 + colb;
            a[m] = __builtin_bit_cast(bf16x8, *(const uint4*)(Wb + row*256 + kf));
        }
        #pragma unroll
        for (int n=0;n<4;++n) {
            int ee = n*16 + colb;
            b[n] = __builtin_bit_cast(bf16x8,
                     *(const uint4*)&Vs[(unsigned)(ee*256 + kf) ^ (unsigned)((ee&7)<<3)]);
        }
        #pragma unroll
        for (int m=0;m<4;++m)
            #pragma unroll
            for (int n=0;n<4;++n)
                acc[m][n] = __builtin_amdgcn_mfma_f32_16x16x32_bf16(a[m], b[n], acc[m][n], 0, 0, 0);
    }

    // epilogue: u col-major bf16 + fp64 LN partials
    double ls = 0.0, ls2 = 0.0;
    const int rq = grp*4;
    #pragma unroll
    for (int n=0;n<4;++n) {
        int edge = x0 + n*16 + colb;
        if (edge < E) {
            #pragma unroll
            for (int m=0;m<4;++m) {
                f32x4 v = acc[m][n];
                int r0 = w*64 + m*16 + rq;
                uint2 q;
                q.x = f2bu(v[0]) | (f2bu(v[1]) << 16);
                q.y = f2bu(v[2]) | (f2bu(v[3]) << 16);
                *(uint2*)(ucm + (size_t)edge*256 + r0) = q;
                ls  += (double)v[0] + (double)v[1] + (double)v[2] + (double)v[3];
                ls2 += (double)v[0]*v[0] + (double)v[1]*v[1]
                     + (double)v[2]*v[2] + (double)v[3]*v[3];
            }
        }
    }
    sred[tx] = ls; sred[256+tx] = ls2;
    __syncthreads();
    for (int s=128; s>0; s>>=1) {
        if (tx < s) { sred[tx] += sred[tx+s]; sred[256+tx] += sred[256+tx+s]; }
        __syncthreads();
    }
    if (tx == 0) {
        redp[2*(size_t)blockIdx.x]     = sred[0];
        redp[2*(size_t)blockIdx.x + 1] = sred[256];
    }
}

// ============ MFMA edge GEMM2: y = W2[128x256] @ relu(LN(u)); xe += h*y =========
template<int YM>   // 2 = f32 y, 1 = bf16 y
__launch_bounds__(256)
__global__ void mfma_mm2_edge(const bf16* __restrict__ Wb2,  // [128 o][256 k]
                              const bf16* __restrict__ ucm,  // [E][256] bf16
                              const float* __restrict__ ln,
                              float* __restrict__ xe,        // [E][128] f32 col-major RMW
                              void* __restrict__ yv,         // [E][128] col-major
                              int E)
{
    __shared__ __align__(16) unsigned short Vs[64*256];
    const int tx = threadIdx.x;
    const int x0 = blockIdx.x * 64;
    const int es = tx & 63, cg = tx >> 6;
    const int xedge = x0 + es;
    const bool ev = xedge < E;
    const float mean = ln[0], rstd = ln[1];
    const unsigned swz = (unsigned)((es & 7) << 3);

    #pragma unroll
    for (int p = 0; p < 8; ++p) {
        int k0 = p*32 + cg*8;
        uint4 q = make_uint4(0,0,0,0);
        if (ev) {
            uint4 r = *(const uint4*)(ucm + (size_t)xedge*256 + k0);
            float f0 = __uint_as_float(r.x << 16), f1 = __uint_as_float(r.x & 0xffff0000u);
            float f2 = __uint_as_float(r.y << 16), f3 = __uint_as_float(r.y & 0xffff0000u);
            float f4 = __uint_as_float(r.z << 16), f5 = __uint_as_float(r.z & 0xffff0000u);
            float f6 = __uint_as_float(r.w << 16), f7 = __uint_as_float(r.w & 0xffff0000u);
            f0 = fmaxf(0.f,(f0-mean)*rstd); f1 = fmaxf(0.f,(f1-mean)*rstd);
            f2 = fmaxf(0.f,(f2-mean)*rstd); f3 = fmaxf(0.f,(f3-mean)*rstd);
            f4 = fmaxf(0.f,(f4-mean)*rstd); f5 = fmaxf(0.f,(f5-mean)*rstd);
            f6 = fmaxf(0.f,(f6-mean)*rstd); f7 = fmaxf(0.f,(f7-mean)*rstd);
            q.x = f2bu(f0) | (f2bu(f1) << 16);
            q.y = f2bu(f2) | (f2bu(f3) << 16);
            q.z = f2bu(f4) | (f2bu(f5) << 16);
            q.w = f2bu(f6) | (f2bu(f7) << 16);
        }
        *(uint4*)&Vs[(unsigned)(es*256 + k0) ^ swz] = q;
    }
    __syncthreads();

    const int w = tx >> 6, l = tx & 63;
    const int colb = l & 15, grp = l >> 4;
    f32x4 acc[2][4];
    #pragma unroll
    for (int m=0;m<2;++m)
        #pragma unroll
        for (int n=0;n<4;++n) acc[m][n] = (f32x4){0.f,0.f,0.f,0.f};

    #pragma unroll
    for (int kc = 0; kc < 8; ++kc) {
        const int kf = kc*32 + grp*8;
        bf16x8 a[2], b[4];
        #pragma unroll
        for (int m=0;m<2;++m) {
            int row = w*32 + m*16 + colb;
            a[m] = __builtin_bit_cast(bf16x8, *(const uint4*)(Wb2 + row*256 + kf));
        }
        #pragma unroll
        for (int n=0;n<4;++n) {
            int ee = n*16 + colb;
            b[n] = __builtin_bit_cast(bf16x8,
                     *(const uint4*)&Vs[(unsigned)(ee*256 + kf) ^ (unsigned)((ee&7)<<3)]);
        }
        #pragma unroll
        for (int m=0;m<2;++m)
            #pragma unroll
            for (int n=0;n<4;++n)
                acc[m][n] = __builtin_amdgcn_mfma_f32_16x16x32_bf16(a[m], b[n], acc[m][n], 0, 0, 0);
    }

    const int rq = grp*4;
    #pragma unroll
    for (int n=0;n<4;++n) {
        int edge = x0 + n*16 + colb;
        if (edge < E) {
            #pragma unroll
            for (int m=0;m<2;++m) {
                f32x4 v = acc[m][n];
                int r0 = w*32 + m*16 + rq;
                if constexpr (YM == 2) {
                    *(float4*)((float*)yv + (size_t)edge*128 + r0) =
                        make_float4(v[0], v[1], v[2], v[3]);
                } else {
                    uint2 q;
                    q.x = f2bu(v[0]) | (f2bu(v[1]) << 16);
                    q.y = f2bu(v[2]) | (f2bu(v[3]) << 16);
                    *(uint2*)((bf16*)yv + (size_t)edge*128 + r0) = q;
                }
                float* px = xe + (size_t)edge*128 + r0;
                float4 o = *(float4*)px;
                o.x += HSTEP*v[0]; o.y += HSTEP*v[1];
                o.z += HSTEP*v[2]; o.w += HSTEP*v[3];
                *(float4*)px = o;
            }
        }
    }
}

// ---------------- xe col-major -> row-major f32 output ----------------
__launch_bounds__(256)
__global__ void xe_transpose(const float* __restrict__ xe, float* __restrict__ out, int E)
{
    __shared__ float T[128][65];
    const int tx = threadIdx.x;
    const int x0 = blockIdx.x * 64;
    const int es = tx & 63, cg = tx >> 6;
    #pragma unroll
    for (int p = 0; p < 8; ++p) {
        int c = cg*4 + p*16;
        if (x0 + es < E) {
            float4 v = *(const float4*)(xe + (size_t)(x0+es)*128 + c);
            T[c+0][es] = v.x; T[c+1][es] = v.y; T[c+2][es] = v.z; T[c+3][es] = v.w;
        }
    }
    __syncthreads();
    const int c2 = tx >> 1, eo = (tx & 1)*32;
    if (x0 + 64 <= E) {
        #pragma unroll
        for (int q = 0; q < 8; ++q) {
            float4 v = make_float4(T[c2][eo+q*4], T[c2][eo+q*4+1],
                                   T[c2][eo+q*4+2], T[c2][eo+q*4+3]);
            *(float4*)(out + (size_t)c2*E + x0 + eo + q*4) = v;
        }
    } else {
        for (int q = 0; q < 32; ++q) {
            int x = x0 + eo + q;
            if (x < E) out[(size_t)c2*E + x] = T[c2][eo+q];
        }
    }
}

// ---------------- GEMM1 (VALU, openings + node layer) ----------------
enum { M1_OPEN = 0, M1_NODE = 2 };

template<int OC, int IC, int MODE, typename OUT_T>
__launch_bounds__(256)
__global__ void mm1_kernel(const float* __restrict__ Wt,     // [IC][OC] fp32
                           const float* __restrict__ xin,    // OPEN: [IC][n] fp32 rm
                           const float* __restrict__ xn_cm,  // [N][128] col-major
                           const float* __restrict__ si,
                           const float* __restrict__ sj,
                           OUT_T* __restrict__ uout,         // [OC][n] row-major
                           int n, double* __restrict__ redp)
{
    constexpr int RPT = OC/32;
    constexpr int KC = 32, TN = 64;
    __shared__ float lv[KC][TN];
    __shared__ double sred[512];
    const int tx = threadIdx.x;
    const int tr = tx & 31, tc = tx >> 5;
    const int x0 = blockIdx.x * TN;

    float acc[RPT][8];
    #pragma unroll
    for (int ri=0; ri<RPT; ++ri)
        #pragma unroll
        for (int ei=0; ei<8; ++ei) acc[ri][ei] = 0.f;

    for (int c0 = 0; c0 < IC; c0 += KC) {
        if constexpr (MODE == M1_OPEN) {
            #pragma unroll
            for (int k=0; k<2; ++k) {
                int id = k*256 + tx;
                int xq = id & 15, cc = id >> 4;
                int x = x0 + xq*4;
                const float* p = xin + (size_t)(c0+cc)*n + x;
                float4 q;
                if (x + 3 < n) q = *(const float4*)p;
                else {
                    q.x = (x  <n)?p[0]:0.f; q.y = (x+1<n)?p[1]:0.f;
                    q.z = (x+2<n)?p[2]:0.f; q.w = (x+3<n)?p[3]:0.f;
                }
                *(float4*)&lv[cc][xq*4] = q;
            }
        } else {              // M1_NODE: [0.5*(si+sj); si-sj; xn] col-major
            #pragma unroll
            for (int k=0; k<2; ++k) {
                int id = k*256 + tx;
                int xx = id & 63, cg = id >> 6;
                int x = x0 + xx;
                int c = c0 + cg*4;
                float4 q;
                if (x < n) {
                    if (c0 < 128) {
                        float4 a = *(const float4*)(si + (size_t)x*128 + c);
                        float4 b = *(const float4*)(sj + (size_t)x*128 + c);
                        q.x = 0.5f*(a.x+b.x); q.y = 0.5f*(a.y+b.y);
                        q.z = 0.5f*(a.z+b.z); q.w = 0.5f*(a.w+b.w);
                    } else if (c0 < 256) {
                        float4 a = *(const float4*)(si + (size_t)x*128 + (c-128));
                        float4 b = *(const float4*)(sj + (size_t)x*128 + (c-128));
                        q.x = a.x-b.x; q.y = a.y-b.y; q.z = a.z-b.z; q.w = a.w-b.w;
                    } else {
                        q = *(const float4*)(xn_cm + (size_t)x*128 + (c-256));
                    }
                } else { q.x=q.y=q.z=q.w=0.f; }
                lv[cg*4+0][xx]=q.x; lv[cg*4+1][xx]=q.y;
                lv[cg*4+2][xx]=q.z; lv[cg*4+3][xx]=q.w;
            }
        }
        __syncthreads();
        for (int cc=0; cc<KC; ++cc) {
            const float* wrow = Wt + (size_t)(c0+cc)*OC + tr*RPT;
            float w[RPT];
            #pragma unroll
            for (int ri=0; ri<RPT; ++ri) w[ri] = wrow[ri];
            float vv[8];
            #pragma unroll
            for (int ei=0; ei<8; ++ei) vv[ei] = lv[cc][tc*8+ei];
            #pragma unroll
            for (int ri=0; ri<RPT; ++ri)
                #pragma unroll
                for (int ei=0; ei<8; ++ei)
                    acc[ri][ei] = fmaf(w[ri], vv[ei], acc[ri][ei]);
        }
        __syncthreads();
    }

    double ls = 0.0, ls2 = 0.0;
    const bool full = (x0 + TN <= n);
    if (full) {
        #pragma unroll
        for (int ri=0; ri<RPT; ++ri) {
            int r = tr*RPT + ri;
            store8(uout + (size_t)r*n + x0 + tc*8, acc[ri]);
            #pragma unroll
            for (int ei=0; ei<8; ++ei){ double y = acc[ri][ei]; ls += y; ls2 += y*y; }
        }
    } else {
        #pragma unroll
        for (int ri=0; ri<RPT; ++ri) {
            int r = tr*RPT + ri;
            #pragma unroll
            for (int ei=0; ei<8; ++ei) {
                int x = x0 + tc*8 + ei;
                if (x < n) {
                    float y = acc[ri][ei];
                    stor1(uout + (size_t)r*n + x, y);
                    ls += y; ls2 += (double)y*y;
                }
            }
        }
    }
    sred[tx] = ls; sred[256+tx] = ls2;
    __syncthreads();
    for (int s=128; s>0; s>>=1) {
        if (tx < s) { sred[tx] += sred[tx+s]; sred[256+tx] += sred[256+tx+s]; }
        __syncthreads();
    }
    if (tx == 0) {
        redp[2*(size_t)blockIdx.x]     = sred[0];
        redp[2*(size_t)blockIdx.x + 1] = sred[256];
    }
}

// ---------------- GEMM2 (VALU, openings + node layer + final) ----------------
enum { IN_RM_BF16 = 0, IN_RM_F32 = 1, IN_CM_F32 = 2 };
enum { EPI_STORE_CM = 0, EPI_NODE = 1, EPI_OUT = 2 };

template<int OC, int IC, int INMODE, int EPI, bool LNRELU>
__launch_bounds__(256)
__global__ void mm2_kernel(const float* __restrict__ Wt,     // [IC][OC] fp32
                           const void*  __restrict__ uin,
                           const float* __restrict__ ln,
                           float* __restrict__ dstA,         // xn_cm or xe_cm
                           bf16*  __restrict__ xnb,          // optional bf16 shadow
                           float* __restrict__ outb,         // fp32 out (EPI_OUT)
                           int n)
{
    constexpr int RPT = OC/32;
    constexpr int KC = 32, TN = 64;
    __shared__ float lv[KC][TN];
    const int tx = threadIdx.x;
    const int tr = tx & 31, tc = tx >> 5;
    const int x0 = blockIdx.x * TN;

    float mean = 0.f, rstd = 1.f;
    if constexpr (LNRELU) { mean = ln[0]; rstd = ln[1]; }

    float acc[RPT][8];
    #pragma unroll
    for (int ri=0; ri<RPT; ++ri)
        #pragma unroll
        for (int ei=0; ei<8; ++ei) acc[ri][ei] = 0.f;

    for (int c0 = 0; c0 < IC; c0 += KC) {
        if constexpr (INMODE == IN_CM_F32) {
            #pragma unroll
            for (int k=0; k<2; ++k) {
                int id = k*256 + tx;
                int xx = id & 63, cg = id >> 6;
                int x = x0 + xx;
                float4 q;
                if (x < n) q = *(const float4*)((const float*)uin + (size_t)x*128 + c0 + cg*4);
                else { q.x=q.y=q.z=q.w=0.f; }
                if constexpr (LNRELU) {
                    q.x = fmaxf(0.f,(q.x-mean)*rstd); q.y = fmaxf(0.f,(q.y-mean)*rstd);
                    q.z = fmaxf(0.f,(q.z-mean)*rstd); q.w = fmaxf(0.f,(q.w-mean)*rstd);
                }
                lv[cg*4+0][xx]=q.x; lv[cg*4+1][xx]=q.y;
                lv[cg*4+2][xx]=q.z; lv[cg*4+3][xx]=q.w;
            }
        } else {
            #pragma unroll
            for (int k=0; k<2; ++k) {
                int id = k*256 + tx;
                int xq = id & 15, cc = id >> 4;
                int x = x0 + xq*4;
                int c = c0 + cc;
                float4 q;
                if constexpr (INMODE == IN_RM_F32) {
                    const float* p = (const float*)uin + (size_t)c*n + x;
                    if (x + 3 < n) q = *(const float4*)p;
                    else {
                        q.x = (x  <n)?p[0]:0.f; q.y = (x+1<n)?p[1]:0.f;
                        q.z = (x+2<n)?p[2]:0.f; q.w = (x+3<n)?p[3]:0.f;
                    }
                } else {
                    const bf16* p = (const bf16*)uin + (size_t)c*n + x;
                    if (x + 3 < n) q = load4bf(p);
                    else {
                        q.x = (x  <n)?b2f(p[0]):0.f; q.y = (x+1<n)?b2f(p[1]):0.f;
                        q.z = (x+2<n)?b2f(p[2]):0.f; q.w = (x+3<n)?b2f(p[3]):0.f;
                    }
                }
                if constexpr (LNRELU) {
                    q.x = fmaxf(0.f,(q.x-mean)*rstd); q.y = fmaxf(0.f,(q.y-mean)*rstd);
                    q.z = fmaxf(0.f,(q.z-mean)*rstd); q.w = fmaxf(0.f,(q.w-mean)*rstd);
                }
                *(float4*)&lv[cc][xq*4] = q;
            }
        }
        __syncthreads();
        for (int cc=0; cc<KC; ++cc) {
            const float* wrow = Wt + (size_t)(c0+cc)*OC + tr*RPT;
            float w[RPT];
            #pragma unroll
            for (int ri=0; ri<RPT; ++ri) w[ri] = wrow[ri];
            float vv[8];
            #pragma unroll
            for (int ei=0; ei<8; ++ei) vv[ei] = lv[cc][tc*8+ei];
            #pragma unroll
            for (int ri=0; ri<RPT; ++ri)
                #pragma unroll
                for (int ei=0; ei<8; ++ei)
                    acc[ri][ei] = fmaf(w[ri], vv[ei], acc[ri][ei]);
        }
        __syncthreads();
    }

    const bool full = (x0 + TN <= n);
    if constexpr (EPI == EPI_STORE_CM) {           // col-major, RPT==4
        #pragma unroll
        for (int ei=0; ei<8; ++ei) {
            int x = x0 + tc*8 + ei;
            if (x < n) {
                float4 q = make_float4(acc[0][ei],acc[1][ei],acc[2][ei],acc[3][ei]);
                *(float4*)(dstA + (size_t)x*128 + tr*4) = q;
                if (xnb) {
                    uint2 bq;
                    bq.x = f2bu(q.x) | (f2bu(q.y) << 16);
                    bq.y = f2bu(q.z) | (f2bu(q.w) << 16);
                    *(uint2*)(xnb + (size_t)x*128 + tr*4) = bq;
                }
            }
        }
    } else if constexpr (EPI == EPI_NODE) {        // xn += h*y (col-major, RPT==4)
        #pragma unroll
        for (int ei=0; ei<8; ++ei) {
            int x = x0 + tc*8 + ei;
            if (x < n) {
                float* p = dstA + (size_t)x*128 + tr*4;
                float4 q = *(float4*)p;
                q.x += HSTEP*acc[0][ei]; q.y += HSTEP*acc[1][ei];
                q.z += HSTEP*acc[2][ei]; q.w += HSTEP*acc[3][ei];
                *(float4*)p = q;
                if (xnb) {
                    uint2 bq;
                    bq.x = f2bu(q.x) | (f2bu(q.y) << 16);
                    bq.y = f2bu(q.z) | (f2bu(q.w) << 16);
                    *(uint2*)(xnb + (size_t)x*128 + tr*4) = bq;
                }
            }
        }
    } else {                                       // EPI_OUT: fp32 row-major
        #pragma unroll
        for (int ri=0; ri<RPT; ++ri) {
            int r = tr*RPT + ri;
            if (full) {
                store8(outb + (size_t)r*n + x0 + tc*8, acc[ri]);
            } else {
                #pragma unroll
                for (int ei=0; ei<8; ++ei) {
                    int x = x0 + tc*8 + ei;
                    if (x < n) outb[(size_t)r*n + x] = acc[ri][ei];
                }
            }
        }
    }
}

extern "C" void kernel_launch(void* const* d_in, const int* in_sizes, int n_in,
                              void* d_out, int out_size, void* d_ws, size_t ws_size,
                              hipStream_t stream)
{
    const int N = in_sizes[0] / 32;          // 50000
    const int E = in_sizes[1] / 32;          // 500000
    const int NL = in_sizes[9] / (256*384);  // 4

    const float* xn_in = (const float*)d_in[0];
    const float* xe_in = (const float*)d_in[1];
    const int*   iInd  = (const int*)d_in[2];
    const int*   jInd  = (const int*)d_in[3];
    const float* K1N = (const float*)d_in[4];
    const float* K2N = (const float*)d_in[5];
    const float* K1E = (const float*)d_in[6];
    const float* K2E = (const float*)d_in[7];
    const float* KNo = (const float*)d_in[8];
    const float* KE1 = (const float*)d_in[9];
    const float* KE2 = (const float*)d_in[10];
    const float* KN1 = (const float*)d_in[11];
    const float* KN2 = (const float*)d_in[12];

    char* base = (char*)d_ws;
    size_t off = 0;
    auto carve = [&](size_t bytes)->void* {
        void* p = base + off; off += (bytes + 255) & ~(size_t)255; return p;
    };
    float* xn  = (float*)carve((size_t)128*N*sizeof(float));  // col-major [N][128]
    float* xe  = (float*)carve((size_t)128*E*sizeof(float));  // col-major [E][128]
    bf16*  u   = (bf16*) carve((size_t)256*E*sizeof(bf16));   // col-major [E][256] (edge)
    float* un  = (float*)u;                                   // alias: node u [256][N] f32 rm
    float* si  = (float*)carve((size_t)128*N*sizeof(float));
    float* sj  = (float*)carve((size_t)128*N*sizeof(float));
    float* wts = (float*)carve(200000*sizeof(float));
    bf16*  Wb  = (bf16*) carve((size_t)256*256*sizeof(bf16)); // folded KE1 bf16 [o][k]
    bf16*  Wb2 = (bf16*) carve((size_t)128*256*sizeof(bf16)); // KE2 bf16 [o][k]
    bf16*  xnb = (bf16*) carve((size_t)128*N*sizeof(bf16));   // xn bf16 shadow [N][128]
    double* redp = (double*)carve(2*8192*sizeof(double));
    float* lnp = (float*)carve(256);
    int* cnt      = (int*)carve((size_t)N*sizeof(int));
    int* rowptr_i = (int*)carve((size_t)(N+1)*sizeof(int));
    int* rowptr_j = (int*)carve((size_t)(N+1)*sizeof(int));
    int* cur_i    = (int*)carve((size_t)N*sizeof(int));
    int* cur_j    = (int*)carve((size_t)N*sizeof(int));
    int* eadj_i   = (int*)carve((size_t)E*sizeof(int));
    int* eadj_j   = (int*)carve((size_t)E*sizeof(int));

    if (ws_size < off) return;

    // y buffer: col-major [E][128]; prefer fp32, fall back bf16.
    int ymode = 0;
    void* y = nullptr;
    if (off + (size_t)128*E*sizeof(float) <= ws_size) { y = base + off; ymode = 2; }
    else if (off + (size_t)128*E*sizeof(bf16) <= ws_size) { y = base + off; ymode = 1; }
    if (!ymode) return;

    float* K1Nt = wts;                 // [32][128]
    float* K2Nt = K1Nt + 32*128;       // [128][128]
    float* K1Et = K2Nt + 128*128;      // [32][128]
    float* K2Et = K1Et + 32*128;       // [128][128]
    float* KNoT = K2Et + 128*128;      // [128][64]
    float* KN1t = KNoT + 128*64;       // [384][256]
    float* KN2t = KN1t + 384*256;      // [256][128]

    wt_transpose<<<dim3((128*32 +255)/256),dim3(256),0,stream>>>(K1N, K1Nt, 128, 32);
    wt_transpose<<<dim3((128*128+255)/256),dim3(256),0,stream>>>(K2N, K2Nt, 128, 128);
    wt_transpose<<<dim3((128*32 +255)/256),dim3(256),0,stream>>>(K1E, K1Et, 128, 32);
    wt_transpose<<<dim3((128*128+255)/256),dim3(256),0,stream>>>(K2E, K2Et, 128, 128);
    wt_transpose<<<dim3((64*128 +255)/256),dim3(256),0,stream>>>(KNo, KNoT, 64, 128);

    const int gN = (N + 63)/64, gE = (E + 63)/64;
    const int gEb = (E + 255)/256;

    // build CSR once
    (void)hipMemsetAsync(cnt, 0, (size_t)N*sizeof(int), stream);
    csr_hist<<<gEb,256,0,stream>>>(iInd, cnt, E);
    csr_scan<<<1,256,0,stream>>>(cnt, rowptr_i, cur_i, N);
    csr_fill<<<gEb,256,0,stream>>>(iInd, cur_i, eadj_i, E);
    (void)hipMemsetAsync(cnt, 0, (size_t)N*sizeof(int), stream);
    csr_hist<<<gEb,256,0,stream>>>(jInd, cnt, E);
    csr_scan<<<1,256,0,stream>>>(cnt, rowptr_j, cur_j, N);
    csr_fill<<<gEb,256,0,stream>>>(jInd, cur_j, eadj_j, E);

    // ---- opening: nodes (u row-major [128][N] bf16) ----
    mm1_kernel<128,32,M1_OPEN,bf16><<<gN,256,0,stream>>>(
        K1Nt, xn_in, nullptr, nullptr, nullptr, u, N, redp);
    ln_reduce<<<1,256,0,stream>>>(redp, gN, lnp, 128.0*N);
    mm2_kernel<128,128,IN_RM_BF16,EPI_STORE_CM,true><<<gN,256,0,stream>>>(
        K2Nt, u, lnp, xn, xnb, nullptr, N);

    // ---- opening: edges (u row-major [128][E] bf16; xe col-major out) ----
    mm1_kernel<128,32,M1_OPEN,bf16><<<gE,256,0,stream>>>(
        K1Et, xe_in, nullptr, nullptr, nullptr, u, E, redp);
    ln_reduce<<<1,256,0,stream>>>(redp, gE, lnp, 128.0*E);
    mm2_kernel<128,128,IN_RM_BF16,EPI_STORE_CM,true><<<gE,256,0,stream>>>(
        K2Et, u, lnp, xe, nullptr, nullptr, E);

    for (int l = 0; l < NL; ++l) {
        wt_ke1_bf<<<dim3(256),dim3(256),0,stream>>>(KE1 + (size_t)l*256*384, Wb);
        wt_cast_bf<<<dim3(128),dim3(256),0,stream>>>(KE2 + (size_t)l*128*256, Wb2, 128*256);
        wt_transpose<<<dim3((256*384+255)/256),dim3(256),0,stream>>>(KN1 + (size_t)l*256*384, KN1t, 256, 384);
        wt_transpose<<<dim3((128*256+255)/256),dim3(256),0,stream>>>(KN2 + (size_t)l*128*256, KN2t, 128, 256);

        // edge double_layer (MFMA)
        mfma_mm1_edge<<<gE,256,0,stream>>>(Wb, xnb, xe, iInd, u, E, redp);
        ln_reduce<<<1,256,0,stream>>>(redp, gE, lnp, 256.0*E);
        if (ymode == 2) {
            mfma_mm2_edge<2><<<gE,256,0,stream>>>(Wb2, u, lnp, xe, y, E);
            gather_nodes<false><<<(N+3)/4,256,0,stream>>>(y, rowptr_i, eadj_i, si, N);
            gather_nodes<false><<<(N+3)/4,256,0,stream>>>(y, rowptr_j, eadj_j, sj, N);
        } else {
            mfma_mm2_edge<1><<<gE,256,0,stream>>>(Wb2, u, lnp, xe, y, E);
            gather_nodes<true><<<(N+3)/4,256,0,stream>>>(y, rowptr_i, eadj_i, si, N);
            gather_nodes<true><<<(N+3)/4,256,0,stream>>>(y, rowptr_j, eadj_j, sj, N);
        }

        // node double_layer (VALU)
        mm1_kernel<256,384,M1_NODE,float><<<gN,256,0,stream>>>(
            KN1t, nullptr, xn, si, sj, un, N, redp);
        ln_reduce<<<1,256,0,stream>>>(redp, gN, lnp, 256.0*N);
        mm2_kernel<128,256,IN_RM_F32,EPI_NODE,true><<<gN,256,0,stream>>>(
            KN2t, un, lnp, xn, xnb, nullptr, N);
    }

    // ---- final: xn_out = KNout @ xn ; xe transpose to row-major ----
    mm2_kernel<64,128,IN_CM_F32,EPI_OUT,false><<<gN,256,0,stream>>>(
        KNoT, xn, nullptr, nullptr, nullptr, (float*)d_out, N);
    xe_transpose<<<gE,256,0,stream>>>(xe, (float*)d_out + (size_t)64*N, E);
}

// Round 3
// 4172.022 us; speedup vs baseline: 2.8909x; 1.2589x over previous
//
#include <hip/hip_runtime.h>
#include <hip/hip_bf16.h>

// gNet: 4-layer graph net, B=1, HID=128, N=50000, E=500000.
// R1: scatter->CSR gather (atomics removed).
// R2: edge GEMMs on MFMA bf16; u col-major [E][256] bf16; xe col-major f32.
// R3: coalesced staging (4 threads per 512B row, was lane=row strided);
//     node layer + opening mm2s moved to MFMA as well.

typedef __hip_bfloat16 bf16;
typedef __attribute__((ext_vector_type(8))) short bf16x8;
typedef __attribute__((ext_vector_type(4))) float f32x4;

#define HSTEP 0.1f

__device__ __forceinline__ bf16  f2b(float v){ return __float2bfloat16(v); }
__device__ __forceinline__ unsigned int f2bu(float v){
    return (unsigned int)__builtin_bit_cast(unsigned short, __float2bfloat16(v));
}
__device__ __forceinline__ void store8(float* p, const float* a){
    *(float4*)p       = make_float4(a[0],a[1],a[2],a[3]);
    *((float4*)p + 1) = make_float4(a[4],a[5],a[6],a[7]);
}

// decode 8 bf16 (uint4), apply LN+relu, re-encode
__device__ __forceinline__ uint4 lnrelu_pack(uint4 r, float mean, float rstd){
    float f0 = __uint_as_float(r.x << 16), f1 = __uint_as_float(r.x & 0xffff0000u);
    float f2 = __uint_as_float(r.y << 16), f3 = __uint_as_float(r.y & 0xffff0000u);
    float f4 = __uint_as_float(r.z << 16), f5 = __uint_as_float(r.z & 0xffff0000u);
    float f6 = __uint_as_float(r.w << 16), f7 = __uint_as_float(r.w & 0xffff0000u);
    f0 = fmaxf(0.f,(f0-mean)*rstd); f1 = fmaxf(0.f,(f1-mean)*rstd);
    f2 = fmaxf(0.f,(f2-mean)*rstd); f3 = fmaxf(0.f,(f3-mean)*rstd);
    f4 = fmaxf(0.f,(f4-mean)*rstd); f5 = fmaxf(0.f,(f5-mean)*rstd);
    f6 = fmaxf(0.f,(f6-mean)*rstd); f7 = fmaxf(0.f,(f7-mean)*rstd);
    uint4 q;
    q.x = f2bu(f0) | (f2bu(f1) << 16);
    q.y = f2bu(f2) | (f2bu(f3) << 16);
    q.z = f2bu(f4) | (f2bu(f5) << 16);
    q.w = f2bu(f6) | (f2bu(f7) << 16);
    return q;
}
// pack 8 f32 (two float4) -> uint4 bf16
__device__ __forceinline__ uint4 pack8f(float4 a, float4 b){
    uint4 q;
    q.x = f2bu(a.x) | (f2bu(a.y) << 16);
    q.y = f2bu(a.z) | (f2bu(a.w) << 16);
    q.z = f2bu(b.x) | (f2bu(b.y) << 16);
    q.w = f2bu(b.z) | (f2bu(b.w) << 16);
    return q;
}

// ---------------- weight prep ----------------
__global__ void wt_transpose(const float* __restrict__ src, float* __restrict__ dst,
                             int O, int C) {
    int i = blockIdx.x*256 + threadIdx.x;
    if (i >= O*C) return;
    int o = i / C, c = i - o*C;
    dst[c*O + o] = src[i];
}

// KE1 [256][384] -> folded bf16 [256 o][256 k] (row==col==iInd)
__global__ void wt_ke1_bf(const float* __restrict__ src, bf16* __restrict__ dst) {
    int i = blockIdx.x*256 + threadIdx.x;
    if (i >= 256*256) return;
    int o = i >> 8, c = i & 255;
    float v;
    if (c < 128) v = src[o*384 + c] + src[o*384 + 128 + c];
    else         v = src[o*384 + 128 + c];
    dst[i] = f2b(v);
}

__global__ void wt_cast_bf(const float* __restrict__ src, bf16* __restrict__ dst, int cnt) {
    int i = blockIdx.x*256 + threadIdx.x;
    if (i < cnt) dst[i] = f2b(src[i]);
}

// ---------------- CSR build ----------------
__global__ void csr_hist(const int* __restrict__ ind, int* __restrict__ cnt, int E){
    int e = blockIdx.x*256 + threadIdx.x;
    if (e < E) atomicAdd(&cnt[ind[e]], 1);
}

__global__ void csr_scan(const int* __restrict__ cnt, int* __restrict__ rowptr,
                         int* __restrict__ cursor, int Nn)
{
    __shared__ int part[256];
    int tx = threadIdx.x;
    int chunk = (Nn + 255) / 256;
    int a0 = tx * chunk;
    int a1 = a0 + chunk; if (a1 > Nn) a1 = Nn; if (a0 > Nn) a0 = Nn;
    int s = 0;
    for (int i = a0; i < a1; ++i) s += cnt[i];
    part[tx] = s;
    __syncthreads();
    for (int d = 1; d < 256; d <<= 1) {
        int v = (tx >= d) ? part[tx - d] : 0;
        __syncthreads();
        part[tx] += v;
        __syncthreads();
    }
    int run = (tx == 0) ? 0 : part[tx - 1];
    for (int i = a0; i < a1; ++i) {
        rowptr[i] = run; cursor[i] = run;
        run += cnt[i];
    }
    if (tx == 255) rowptr[Nn] = run;
}

__global__ void csr_fill(const int* __restrict__ ind, int* __restrict__ cursor,
                         int* __restrict__ eadj, int E){
    int e = blockIdx.x*256 + threadIdx.x;
    if (e < E) {
        int p = atomicAdd(&cursor[ind[e]], 1);
        eadj[p] = e;
    }
}

// ---------------- gather: s[:,node] = sum_{e in adj(node)} y[:,e] ------------
template<bool YB16>
__launch_bounds__(256)
__global__ void gather_nodes(const void* __restrict__ yv,
                             const int* __restrict__ rowptr,
                             const int* __restrict__ eadj,
                             float* __restrict__ s, int Nn)
{
    int wid  = threadIdx.x >> 6;
    int lane = threadIdx.x & 63;
    int node = blockIdx.x * 4 + wid;
    if (node >= Nn) return;
    int k0 = rowptr[node], k1 = rowptr[node+1];
    float a0 = 0.f, a1 = 0.f;
    for (int k = k0; k < k1; ++k) {
        int e = eadj[k];
        if constexpr (YB16) {
            unsigned int b = *((const unsigned int*)yv + (size_t)e*64 + lane);
            a0 += __uint_as_float(b << 16);
            a1 += __uint_as_float(b & 0xffff0000u);
        } else {
            float2 v = *((const float2*)yv + (size_t)e*64 + lane);
            a0 += v.x; a1 += v.y;
        }
    }
    *(float2*)(s + (size_t)node*128 + lane*2) = make_float2(a0, a1);
}

// ---------------- LN stat reduction ----------------
__global__ void ln_reduce(const double* __restrict__ redp, int nb,
                          float* __restrict__ ln, double cnt)
{
    __shared__ double s0[256], s1[256];
    int tx = threadIdx.x;
    double a = 0.0, b = 0.0;
    for (int i = tx; i < nb; i += 256) { a += redp[2*i]; b += redp[2*i+1]; }
    s0[tx] = a; s1[tx] = b;
    __syncthreads();
    for (int s = 128; s > 0; s >>= 1) {
        if (tx < s) { s0[tx] += s0[tx+s]; s1[tx] += s1[tx+s]; }
        __syncthreads();
    }
    if (tx == 0) {
        double m = s0[0] / cnt;
        double var = s1[0] / cnt - m*m;
        if (var < 0.0) var = 0.0;
        ln[0] = (float)m;
        ln[1] = (float)(1.0 / sqrt(var + 1e-5));
    }
}

// ============ MFMA GEMM1 edge: u[E][256] = W1[256x256] @ [xnb(iInd); xe] =====
__launch_bounds__(256)
__global__ void mfma_mm1_edge(const bf16* __restrict__ Wb,   // [256 o][256 k]
                              const bf16* __restrict__ xnb,  // [N][128] bf16
                              const float* __restrict__ xe,  // [E][128] f32 cm
                              const int* __restrict__ iInd,
                              bf16* __restrict__ ucm,        // [E][256] bf16
                              int E, double* __restrict__ redp)
{
    __shared__ __align__(16) unsigned short Vs[64*256];
    __shared__ double sred[512];
    const int tx = threadIdx.x;
    const int x0 = blockIdx.x * 64;
    const int e = tx >> 2, q4 = tx & 3;
    const int xedge = x0 + e;
    const bool ev = xedge < E;
    const int gidx = ev ? iInd[xedge] : 0;
    const unsigned swz = (unsigned)((e & 7) << 3);

    // node part k=0..127 (bf16 gather; lane-quads contiguous 64B)
    #pragma unroll
    for (int p = 0; p < 4; ++p) {
        int k0 = q4*8 + p*32;
        uint4 v = make_uint4(0,0,0,0);
        if (ev) v = *(const uint4*)(xnb + (size_t)gidx*128 + k0);
        *(uint4*)&Vs[(unsigned)(e*256 + k0) ^ swz] = v;
    }
    // edge part k=128..255 (f32 cm -> bf16)
    #pragma unroll
    for (int p = 0; p < 4; ++p) {
        int k0 = q4*8 + p*32;
        uint4 v = make_uint4(0,0,0,0);
        if (ev) {
            const float* s = xe + (size_t)xedge*128 + k0;
            v = pack8f(*(const float4*)s, *(const float4*)(s + 4));
        }
        *(uint4*)&Vs[(unsigned)(e*256 + 128 + k0) ^ swz] = v;
    }
    __syncthreads();

    const int w = tx >> 6, l = tx & 63;
    const int colb = l & 15, grp = l >> 4;
    f32x4 acc[4][4];
    #pragma unroll
    for (int m=0;m<4;++m)
        #pragma unroll
        for (int n=0;n<4;++n) acc[m][n] = (f32x4){0.f,0.f,0.f,0.f};

    #pragma unroll
    for (int kc = 0; kc < 8; ++kc) {
        const int kf = kc*32 + grp*8;
        bf16x8 a[4], b[4];
        #pragma unroll
        for (int m=0;m<4;++m) {
            int row = w*64 + m*16 + colb;
            a[m] = __builtin_bit_cast(bf16x8, *(const uint4*)(Wb + row*256 + kf));
        }
        #pragma unroll
        for (int n=0;n<4;++n) {
            int ee = n*16 + colb;
            b[n] = __builtin_bit_cast(bf16x8,
                     *(const uint4*)&Vs[(unsigned)(ee*256 + kf) ^ (unsigned)((ee&7)<<3)]);
        }
        #pragma unroll
        for (int m=0;m<4;++m)
            #pragma unroll
            for (int n=0;n<4;++n)
                acc[m][n] = __builtin_amdgcn_mfma_f32_16x16x32_bf16(a[m], b[n], acc[m][n], 0, 0, 0);
    }

    double ls = 0.0, ls2 = 0.0;
    const int rq = grp*4;
    #pragma unroll
    for (int n=0;n<4;++n) {
        int edge = x0 + n*16 + colb;
        if (edge < E) {
            #pragma unroll
            for (int m=0;m<4;++m) {
                f32x4 v = acc[m][n];
                int r0 = w*64 + m*16 + rq;
                uint2 q;
                q.x = f2bu(v[0]) | (f2bu(v[1]) << 16);
                q.y = f2bu(v[2]) | (f2bu(v[3]) << 16);
                *(uint2*)(ucm + (size_t)edge*256 + r0) = q;
                ls  += (double)v[0] + (double)v[1] + (double)v[2] + (double)v[3];
                ls2 += (double)v[0]*v[0] + (double)v[1]*v[1]
                     + (double)v[2]*v[2] + (double)v[3]*v[3];
            }
        }
    }
    sred[tx] = ls; sred[256+tx] = ls2;
    __syncthreads();
    for (int s=128; s>0; s>>=1) {
        if (tx < s) { sred[tx] += sred[tx+s]; sred[256+tx] += sred[256+tx+s]; }
        __syncthreads();
    }
    if (tx == 0) {
        redp[2*(size_t)blockIdx.x]     = sred[0];
        redp[2*(size_t)blockIdx.x + 1] = sred[256];
    }
}

// ============ MFMA GEMM1 node: u[N][256] = KN1[256x384] @ [ave; div; xn] =====
__launch_bounds__(256)
__global__ void mfma_mm1_node(const bf16* __restrict__ Wb,   // [256 o][384 k]
                              const float* __restrict__ si,  // [N][128] f32 cm
                              const float* __restrict__ sj,
                              const float* __restrict__ xn,  // [N][128] f32 cm
                              bf16* __restrict__ ucm,        // [N][256] bf16
                              int Nn, double* __restrict__ redp)
{
    __shared__ __align__(16) unsigned short Vs[64*384];
    __shared__ double sred[512];
    const int tx = threadIdx.x;
    const int x0 = blockIdx.x * 64;
    const int e = tx >> 2, q4 = tx & 3;
    const int node = x0 + e;
    const bool nv = node < Nn;
    const unsigned swz = (unsigned)((e & 7) << 3);

    #pragma unroll
    for (int p = 0; p < 4; ++p) {
        int k0 = q4*8 + p*32;
        uint4 va = make_uint4(0,0,0,0), vd = va;
        if (nv) {
            const float* ps = si + (size_t)node*128 + k0;
            const float* pt = sj + (size_t)node*128 + k0;
            float4 a0 = *(const float4*)ps, a1 = *(const float4*)(ps+4);
            float4 b0 = *(const float4*)pt, b1 = *(const float4*)(pt+4);
            float4 av0 = make_float4(0.5f*(a0.x+b0.x),0.5f*(a0.y+b0.y),
                                     0.5f*(a0.z+b0.z),0.5f*(a0.w+b0.w));
            float4 av1 = make_float4(0.5f*(a1.x+b1.x),0.5f*(a1.y+b1.y),
                                     0.5f*(a1.z+b1.z),0.5f*(a1.w+b1.w));
            float4 dv0 = make_float4(a0.x-b0.x,a0.y-b0.y,a0.z-b0.z,a0.w-b0.w);
            float4 dv1 = make_float4(a1.x-b1.x,a1.y-b1.y,a1.z-b1.z,a1.w-b1.w);
            va = pack8f(av0, av1);
            vd = pack8f(dv0, dv1);
        }
        *(uint4*)&Vs[(unsigned)(e*384 + k0) ^ swz] = va;
        *(uint4*)&Vs[(unsigned)(e*384 + 128 + k0) ^ swz] = vd;
    }
    #pragma unroll
    for (int p = 0; p < 4; ++p) {
        int k0 = q4*8 + p*32;
        uint4 v = make_uint4(0,0,0,0);
        if (nv) {
            const float* s = xn + (size_t)node*128 + k0;
            v = pack8f(*(const float4*)s, *(const float4*)(s + 4));
        }
        *(uint4*)&Vs[(unsigned)(e*384 + 256 + k0) ^ swz] = v;
    }
    __syncthreads();

    const int w = tx >> 6, l = tx & 63;
    const int colb = l & 15, grp = l >> 4;
    f32x4 acc[4][4];
    #pragma unroll
    for (int m=0;m<4;++m)
        #pragma unroll
        for (int n=0;n<4;++n) acc[m][n] = (f32x4){0.f,0.f,0.f,0.f};

    #pragma unroll
    for (int kc = 0; kc < 12; ++kc) {
        const int kf = kc*32 + grp*8;
        bf16x8 a[4], b[4];
        #pragma unroll
        for (int m=0;m<4;++m) {
            int row = w*64 + m*16 + colb;
            a[m] = __builtin_bit_cast(bf16x8, *(const uint4*)(Wb + row*384 + kf));
        }
        #pragma unroll
        for (int n=0;n<4;++n) {
            int ee = n*16 + colb;
            b[n] = __builtin_bit_cast(bf16x8,
                     *(const uint4*)&Vs[(unsigned)(ee*384 + kf) ^ (unsigned)((ee&7)<<3)]);
        }
        #pragma unroll
        for (int m=0;m<4;++m)
            #pragma unroll
            for (int n=0;n<4;++n)
                acc[m][n] = __builtin_amdgcn_mfma_f32_16x16x32_bf16(a[m], b[n], acc[m][n], 0, 0, 0);
    }

    double ls = 0.0, ls2 = 0.0;
    const int rq = grp*4;
    #pragma unroll
    for (int n=0;n<4;++n) {
        int nd = x0 + n*16 + colb;
        if (nd < Nn) {
            #pragma unroll
            for (int m=0;m<4;++m) {
                f32x4 v = acc[m][n];
                int r0 = w*64 + m*16 + rq;
                uint2 q;
                q.x = f2bu(v[0]) | (f2bu(v[1]) << 16);
                q.y = f2bu(v[2]) | (f2bu(v[3]) << 16);
                *(uint2*)(ucm + (size_t)nd*256 + r0) = q;
                ls  += (double)v[0] + (double)v[1] + (double)v[2] + (double)v[3];
                ls2 += (double)v[0]*v[0] + (double)v[1]*v[1]
                     + (double)v[2]*v[2] + (double)v[3]*v[3];
            }
        }
    }
    sred[tx] = ls; sred[256+tx] = ls2;
    __syncthreads();
    for (int s=128; s>0; s>>=1) {
        if (tx < s) { sred[tx] += sred[tx+s]; sred[256+tx] += sred[256+tx+s]; }
        __syncthreads();
    }
    if (tx == 0) {
        redp[2*(size_t)blockIdx.x]     = sred[0];
        redp[2*(size_t)blockIdx.x + 1] = sred[256];
    }
}

// ============ MFMA GEMM2 (OC=128): y = W2 @ relu(LN(u)); fused epilogues =====
enum { E2_EDGE = 0, E2_NODE = 1, E2_XE0 = 2, E2_XN0 = 3 };

template<int IC, int EPI, int YM>
__launch_bounds__(256)
__global__ void mfma_mm2(const bf16* __restrict__ Wb2,  // [128 o][IC k]
                         const bf16* __restrict__ ucm,  // [n][IC] bf16
                         const float* __restrict__ ln,
                         float* __restrict__ dst,       // xe or xn, [n][128] f32 cm
                         void* __restrict__ yv,         // y [E][128] (EDGE)
                         bf16* __restrict__ xnb,        // xn shadow (NODE/XN0)
                         int n)
{
    __shared__ __align__(16) unsigned short Vs[64*IC];
    const int tx = threadIdx.x;
    const int x0 = blockIdx.x * 64;
    const int e = tx >> 2, q4 = tx & 3;
    const int row = x0 + e;
    const bool rv = row < n;
    const float mean = ln[0], rstd = ln[1];
    const unsigned swz = (unsigned)((e & 7) << 3);

    #pragma unroll
    for (int p = 0; p < IC/32; ++p) {
        int k0 = q4*8 + p*32;
        uint4 v = make_uint4(0,0,0,0);
        if (rv) {
            uint4 r = *(const uint4*)(ucm + (size_t)row*IC + k0);
            v = lnrelu_pack(r, mean, rstd);
        }
        *(uint4*)&Vs[(unsigned)(e*IC + k0) ^ swz] = v;
    }
    __syncthreads();

    const int w = tx >> 6, l = tx & 63;
    const int colb = l & 15, grp = l >> 4;
    f32x4 acc[2][4];
    #pragma unroll
    for (int m=0;m<2;++m)
        #pragma unroll
        for (int nn=0;nn<4;++nn) acc[m][nn] = (f32x4){0.f,0.f,0.f,0.f};

    #pragma unroll
    for (int kc = 0; kc < IC/32; ++kc) {
        const int kf = kc*32 + grp*8;
        bf16x8 a[2], b[4];
        #pragma unroll
        for (int m=0;m<2;++m) {
            int rr = w*32 + m*16 + colb;
            a[m] = __builtin_bit_cast(bf16x8, *(const uint4*)(Wb2 + rr*IC + kf));
        }
        #pragma unroll
        for (int nn=0;nn<4;++nn) {
            int ee = nn*16 + colb;
            b[nn] = __builtin_bit_cast(bf16x8,
                     *(const uint4*)&Vs[(unsigned)(ee*IC + kf) ^ (unsigned)((ee&7)<<3)]);
        }
        #pragma unroll
        for (int m=0;m<2;++m)
            #pragma unroll
            for (int nn=0;nn<4;++nn)
                acc[m][nn] = __builtin_amdgcn_mfma_f32_16x16x32_bf16(a[m], b[nn], acc[m][nn], 0, 0, 0);
    }

    const int rq = grp*4;
    #pragma unroll
    for (int nn=0;nn<4;++nn) {
        int x = x0 + nn*16 + colb;
        if (x < n) {
            #pragma unroll
            for (int m=0;m<2;++m) {
                f32x4 v = acc[m][nn];
                int r0 = w*32 + m*16 + rq;
                if constexpr (EPI == E2_EDGE) {
                    if constexpr (YM == 2) {
                        *(float4*)((float*)yv + (size_t)x*128 + r0) =
                            make_float4(v[0], v[1], v[2], v[3]);
                    } else {
                        uint2 q;
                        q.x = f2bu(v[0]) | (f2bu(v[1]) << 16);
                        q.y = f2bu(v[2]) | (f2bu(v[3]) << 16);
                        *(uint2*)((bf16*)yv + (size_t)x*128 + r0) = q;
                    }
                    float* px = dst + (size_t)x*128 + r0;
                    float4 o = *(float4*)px;
                    o.x += HSTEP*v[0]; o.y += HSTEP*v[1];
                    o.z += HSTEP*v[2]; o.w += HSTEP*v[3];
                    *(float4*)px = o;
                } else if constexpr (EPI == E2_XE0) {
                    *(float4*)(dst + (size_t)x*128 + r0) =
                        make_float4(v[0], v[1], v[2], v[3]);
                } else if constexpr (EPI == E2_NODE) {
                    float* px = dst + (size_t)x*128 + r0;
                    float4 o = *(float4*)px;
                    o.x += HSTEP*v[0]; o.y += HSTEP*v[1];
                    o.z += HSTEP*v[2]; o.w += HSTEP*v[3];
                    *(float4*)px = o;
                    uint2 q;
                    q.x = f2bu(o.x) | (f2bu(o.y) << 16);
                    q.y = f2bu(o.z) | (f2bu(o.w) << 16);
                    *(uint2*)(xnb + (size_t)x*128 + r0) = q;
                } else {  // E2_XN0
                    *(float4*)(dst + (size_t)x*128 + r0) =
                        make_float4(v[0], v[1], v[2], v[3]);
                    uint2 q;
                    q.x = f2bu(v[0]) | (f2bu(v[1]) << 16);
                    q.y = f2bu(v[2]) | (f2bu(v[3]) << 16);
                    *(uint2*)(xnb + (size_t)x*128 + r0) = q;
                }
            }
        }
    }
}

// ---------------- opening GEMM1 (VALU, IC=32): u[n][128] bf16 cm --------------
__launch_bounds__(256)
__global__ void mm1_open(const float* __restrict__ Wt,   // [32][128]
                         const float* __restrict__ xin,  // [32][n] f32 rm
                         bf16* __restrict__ ucm,         // [n][128] bf16
                         int n, double* __restrict__ redp)
{
    __shared__ float lv[32][64];
    __shared__ double sred[512];
    const int tx = threadIdx.x;
    const int tr = tx & 31, tc = tx >> 5;
    const int x0 = blockIdx.x * 64;

    float acc[4][8];
    #pragma unroll
    for (int ri=0; ri<4; ++ri)
        #pragma unroll
        for (int ei=0; ei<8; ++ei) acc[ri][ei] = 0.f;

    #pragma unroll
    for (int k=0; k<2; ++k) {
        int id = k*256 + tx;
        int xq = id & 15, cc = id >> 4;
        int x = x0 + xq*4;
        const float* p = xin + (size_t)cc*n + x;
        float4 q;
        if (x + 3 < n) q = *(const float4*)p;
        else {
            q.x = (x  <n)?p[0]:0.f; q.y = (x+1<n)?p[1]:0.f;
            q.z = (x+2<n)?p[2]:0.f; q.w = (x+3<n)?p[3]:0.f;
        }
        *(float4*)&lv[cc][xq*4] = q;
    }
    __syncthreads();
    for (int cc=0; cc<32; ++cc) {
        const float* wrow = Wt + cc*128 + tr*4;
        float w[4] = {wrow[0], wrow[1], wrow[2], wrow[3]};
        float vv[8];
        #pragma unroll
        for (int ei=0; ei<8; ++ei) vv[ei] = lv[cc][tc*8+ei];
        #pragma unroll
        for (int ri=0; ri<4; ++ri)
            #pragma unroll
            for (int ei=0; ei<8; ++ei)
                acc[ri][ei] = fmaf(w[ri], vv[ei], acc[ri][ei]);
    }

    double ls = 0.0, ls2 = 0.0;
    #pragma unroll
    for (int ei=0; ei<8; ++ei) {
        int x = x0 + tc*8 + ei;
        if (x < n) {
            uint2 bq;
            bq.x = f2bu(acc[0][ei]) | (f2bu(acc[1][ei]) << 16);
            bq.y = f2bu(acc[2][ei]) | (f2bu(acc[3][ei]) << 16);
            *(uint2*)(ucm + (size_t)x*128 + tr*4) = bq;
            #pragma unroll
            for (int ri=0; ri<4; ++ri) {
                double y = acc[ri][ei]; ls += y; ls2 += y*y;
            }
        }
    }
    sred[tx] = ls; sred[256+tx] = ls2;
    __syncthreads();
    for (int s=128; s>0; s>>=1) {
        if (tx < s) { sred[tx] += sred[tx+s]; sred[256+tx] += sred[256+tx+s]; }
        __syncthreads();
    }
    if (tx == 0) {
        redp[2*(size_t)blockIdx.x]     = sred[0];
        redp[2*(size_t)blockIdx.x + 1] = sred[256];
    }
}

// ---------------- final: out[64][N] = KNout @ xn (VALU) ----------------
__launch_bounds__(256)
__global__ void final_out(const float* __restrict__ Wt,   // [128 c][64 o]
                          const float* __restrict__ xncm, // [N][128] f32
                          float* __restrict__ out, int n)
{
    __shared__ float lv[32][64];
    const int tx = threadIdx.x;
    const int tr = tx & 31, tc = tx >> 5;
    const int x0 = blockIdx.x * 64;

    float acc[2][8];
    #pragma unroll
    for (int ri=0; ri<2; ++ri)
        #pragma unroll
        for (int ei=0; ei<8; ++ei) acc[ri][ei] = 0.f;

    for (int c0 = 0; c0 < 128; c0 += 32) {
        #pragma unroll
        for (int k=0; k<2; ++k) {
            int id = k*256 + tx;
            int xx = id & 63, cg = id >> 6;
            int x = x0 + xx;
            float4 q;
            if (x < n) q = *(const float4*)(xncm + (size_t)x*128 + c0 + cg*4);
            else { q.x=q.y=q.z=q.w=0.f; }
            lv[cg*4+0][xx]=q.x; lv[cg*4+1][xx]=q.y;
            lv[cg*4+2][xx]=q.z; lv[cg*4+3][xx]=q.w;
        }
        __syncthreads();
        for (int cc=0; cc<32; ++cc) {
            const float* wrow = Wt + (c0+cc)*64 + tr*2;
            float w0 = wrow[0], w1 = wrow[1];
            float vv[8];
            #pragma unroll
            for (int ei=0; ei<8; ++ei) vv[ei] = lv[cc][tc*8+ei];
            #pragma unroll
            for (int ei=0; ei<8; ++ei) {
                acc[0][ei] = fmaf(w0, vv[ei], acc[0][ei]);
                acc[1][ei] = fmaf(w1, vv[ei], acc[1][ei]);
            }
        }
        __syncthreads();
    }

    const bool full = (x0 + 64 <= n);
    #pragma unroll
    for (int ri=0; ri<2; ++ri) {
        int r = tr*2 + ri;
        if (full) {
            store8(out + (size_t)r*n + x0 + tc*8, acc[ri]);
        } else {
            #pragma unroll
            for (int ei=0; ei<8; ++ei) {
                int x = x0 + tc*8 + ei;
                if (x < n) out[(size_t)r*n + x] = acc[ri][ei];
            }
        }
    }
}

// ---------------- xe col-major -> row-major f32 output ----------------
__launch_bounds__(256)
__global__ void xe_transpose(const float* __restrict__ xe, float* __restrict__ out, int E)
{
    __shared__ float T[128][65];
    const int tx = threadIdx.x;
    const int x0 = blockIdx.x * 64;
    const int es = tx & 63, cg = tx >> 6;
    #pragma unroll
    for (int p = 0; p < 8; ++p) {
        int c = cg*4 + p*16;
        if (x0 + es < E) {
            float4 v = *(const float4*)(xe + (size_t)(x0+es)*128 + c);
            T[c+0][es] = v.x; T[c+1][es] = v.y; T[c+2][es] = v.z; T[c+3][es] = v.w;
        }
    }
    __syncthreads();
    const int c2 = tx >> 1, eo = (tx & 1)*32;
    if (x0 + 64 <= E) {
        #pragma unroll
        for (int q = 0; q < 8; ++q) {
            float4 v = make_float4(T[c2][eo+q*4], T[c2][eo+q*4+1],
                                   T[c2][eo+q*4+2], T[c2][eo+q*4+3]);
            *(float4*)(out + (size_t)c2*E + x0 + eo + q*4) = v;
        }
    } else {
        for (int q = 0; q < 32; ++q) {
            int x = x0 + eo + q;
            if (x < E) out[(size_t)c2*E + x] = T[c2][eo+q];
        }
    }
}

extern "C" void kernel_launch(void* const* d_in, const int* in_sizes, int n_in,
                              void* d_out, int out_size, void* d_ws, size_t ws_size,
                              hipStream_t stream)
{
    const int N = in_sizes[0] / 32;          // 50000
    const int E = in_sizes[1] / 32;          // 500000
    const int NL = in_sizes[9] / (256*384);  // 4

    const float* xn_in = (const float*)d_in[0];
    const float* xe_in = (const float*)d_in[1];
    const int*   iInd  = (const int*)d_in[2];
    const int*   jInd  = (const int*)d_in[3];
    const float* K1N = (const float*)d_in[4];
    const float* K2N = (const float*)d_in[5];
    const float* K1E = (const float*)d_in[6];
    const float* K2E = (const float*)d_in[7];
    const float* KNo = (const float*)d_in[8];
    const float* KE1 = (const float*)d_in[9];
    const float* KE2 = (const float*)d_in[10];
    const float* KN1 = (const float*)d_in[11];
    const float* KN2 = (const float*)d_in[12];

    char* base = (char*)d_ws;
    size_t off = 0;
    auto carve = [&](size_t bytes)->void* {
        void* p = base + off; off += (bytes + 255) & ~(size_t)255; return p;
    };
    float* xn  = (float*)carve((size_t)128*N*sizeof(float));  // [N][128] cm
    float* xe  = (float*)carve((size_t)128*E*sizeof(float));  // [E][128] cm
    bf16*  u   = (bf16*) carve((size_t)256*E*sizeof(bf16));   // [n][IC] cm bf16
    float* si  = (float*)carve((size_t)128*N*sizeof(float));
    float* sj  = (float*)carve((size_t)128*N*sizeof(float));
    float* wtsf= (float*)carve((32*128*2 + 128*64)*sizeof(float));
    bf16*  Wb   = (bf16*)carve((size_t)256*256*sizeof(bf16)); // folded KE1
    bf16*  Wb2  = (bf16*)carve((size_t)128*256*sizeof(bf16)); // KE2
    bf16*  Wn1b = (bf16*)carve((size_t)256*384*sizeof(bf16)); // KN1
    bf16*  Wn2b = (bf16*)carve((size_t)128*256*sizeof(bf16)); // KN2
    bf16*  K2Nb = (bf16*)carve((size_t)128*128*sizeof(bf16));
    bf16*  K2Eb = (bf16*)carve((size_t)128*128*sizeof(bf16));
    bf16*  xnb  = (bf16*)carve((size_t)128*N*sizeof(bf16));   // xn shadow
    double* redp = (double*)carve(2*8192*sizeof(double));
    float* lnp = (float*)carve(256);
    int* cnt      = (int*)carve((size_t)N*sizeof(int));
    int* rowptr_i = (int*)carve((size_t)(N+1)*sizeof(int));
    int* rowptr_j = (int*)carve((size_t)(N+1)*sizeof(int));
    int* cur_i    = (int*)carve((size_t)N*sizeof(int));
    int* cur_j    = (int*)carve((size_t)N*sizeof(int));
    int* eadj_i   = (int*)carve((size_t)E*sizeof(int));
    int* eadj_j   = (int*)carve((size_t)E*sizeof(int));

    if (ws_size < off) return;

    int ymode = 0;
    void* y = nullptr;
    if (off + (size_t)128*E*sizeof(float) <= ws_size) { y = base + off; ymode = 2; }
    else if (off + (size_t)128*E*sizeof(bf16) <= ws_size) { y = base + off; ymode = 1; }
    if (!ymode) return;

    float* K1Nt = wtsf;                // [32][128]
    float* K1Et = K1Nt + 32*128;       // [32][128]
    float* KNoT = K1Et + 32*128;       // [128][64]

    wt_transpose<<<dim3((128*32 +255)/256),dim3(256),0,stream>>>(K1N, K1Nt, 128, 32);
    wt_transpose<<<dim3((128*32 +255)/256),dim3(256),0,stream>>>(K1E, K1Et, 128, 32);
    wt_transpose<<<dim3((64*128 +255)/256),dim3(256),0,stream>>>(KNo, KNoT, 64, 128);
    wt_cast_bf<<<dim3(64),dim3(256),0,stream>>>(K2N, K2Nb, 128*128);
    wt_cast_bf<<<dim3(64),dim3(256),0,stream>>>(K2E, K2Eb, 128*128);

    const int gN = (N + 63)/64, gE = (E + 63)/64;
    const int gEb = (E + 255)/256;

    // CSR build once
    (void)hipMemsetAsync(cnt, 0, (size_t)N*sizeof(int), stream);
    csr_hist<<<gEb,256,0,stream>>>(iInd, cnt, E);
    csr_scan<<<1,256,0,stream>>>(cnt, rowptr_i, cur_i, N);
    csr_fill<<<gEb,256,0,stream>>>(iInd, cur_i, eadj_i, E);
    (void)hipMemsetAsync(cnt, 0, (size_t)N*sizeof(int), stream);
    csr_hist<<<gEb,256,0,stream>>>(jInd, cnt, E);
    csr_scan<<<1,256,0,stream>>>(cnt, rowptr_j, cur_j, N);
    csr_fill<<<gEb,256,0,stream>>>(jInd, cur_j, eadj_j, E);

    // ---- opening: nodes ----
    mm1_open<<<gN,256,0,stream>>>(K1Nt, xn_in, u, N, redp);
    ln_reduce<<<1,256,0,stream>>>(redp, gN, lnp, 128.0*N);
    mfma_mm2<128,E2_XN0,2><<<gN,256,0,stream>>>(K2Nb, u, lnp, xn, nullptr, xnb, N);

    // ---- opening: edges ----
    mm1_open<<<gE,256,0,stream>>>(K1Et, xe_in, u, E, redp);
    ln_reduce<<<1,256,0,stream>>>(redp, gE, lnp, 128.0*E);
    mfma_mm2<128,E2_XE0,2><<<gE,256,0,stream>>>(K2Eb, u, lnp, xe, nullptr, nullptr, E);

    for (int l = 0; l < NL; ++l) {
        wt_ke1_bf<<<dim3(256),dim3(256),0,stream>>>(KE1 + (size_t)l*256*384, Wb);
        wt_cast_bf<<<dim3(128),dim3(256),0,stream>>>(KE2 + (size_t)l*128*256, Wb2, 128*256);
        wt_cast_bf<<<dim3(384),dim3(256),0,stream>>>(KN1 + (size_t)l*256*384, Wn1b, 256*384);
        wt_cast_bf<<<dim3(128),dim3(256),0,stream>>>(KN2 + (size_t)l*128*256, Wn2b, 128*256);

        // edge double_layer (MFMA)
        mfma_mm1_edge<<<gE,256,0,stream>>>(Wb, xnb, xe, iInd, u, E, redp);
        ln_reduce<<<1,256,0,stream>>>(redp, gE, lnp, 256.0*E);
        if (ymode == 2) {
            mfma_mm2<256,E2_EDGE,2><<<gE,256,0,stream>>>(Wb2, u, lnp, xe, y, nullptr, E);
            gather_nodes<false><<<(N+3)/4,256,0,stream>>>(y, rowptr_i, eadj_i, si, N);
            gather_nodes<false><<<(N+3)/4,256,0,stream>>>(y, rowptr_j, eadj_j, sj, N);
        } else {
            mfma_mm2<256,E2_EDGE,1><<<gE,256,0,stream>>>(Wb2, u, lnp, xe, y, nullptr, E);
            gather_nodes<true><<<(N+3)/4,256,0,stream>>>(y, rowptr_i, eadj_i, si, N);
            gather_nodes<true><<<(N+3)/4,256,0,stream>>>(y, rowptr_j, eadj_j, sj, N);
        }

        // node double_layer (MFMA)
        mfma_mm1_node<<<gN,256,0,stream>>>(Wn1b, si, sj, xn, u, N, redp);
        ln_reduce<<<1,256,0,stream>>>(redp, gN, lnp, 256.0*N);
        mfma_mm2<256,E2_NODE,2><<<gN,256,0,stream>>>(Wn2b, u, lnp, xn, nullptr, xnb, N);
    }

    // ---- final ----
    final_out<<<gN,256,0,stream>>>(KNoT, xn, (float*)d_out, N);
    xe_transpose<<<gE,256,0,stream>>>(xe, (float*)d_out + (size_t)64*N, E);
}

// Round 4
// 3658.934 us; speedup vs baseline: 3.2963x; 1.1402x over previous
//
#include <hip/hip_runtime.h>
#include <hip/hip_bf16.h>

// gNet: 4-layer graph net, B=1, HID=128, N=50000, E=500000.
// R1: scatter->CSR gather (atomics removed).
// R2: edge GEMMs on MFMA bf16; u col-major [E][256] bf16; xe col-major f32.
// R3: coalesced staging; node layer + opening mm2s on MFMA.
// R4: A-fragment prefetch in K-loops; LN partials via wave shfl-reduce
//     (was 4KB LDS tree); mm1_edge u-store through LDS (streaming 64B);
//     y bf16 (halves gather traffic); gather unrolled x4 (MLP).

typedef __hip_bfloat16 bf16;
typedef __attribute__((ext_vector_type(8))) short bf16x8;
typedef __attribute__((ext_vector_type(4))) float f32x4;

#define HSTEP 0.1f

__device__ __forceinline__ bf16  f2b(float v){ return __float2bfloat16(v); }
__device__ __forceinline__ unsigned int f2bu(float v){
    return (unsigned int)__builtin_bit_cast(unsigned short, __float2bfloat16(v));
}
__device__ __forceinline__ void store8(float* p, const float* a){
    *(float4*)p       = make_float4(a[0],a[1],a[2],a[3]);
    *((float4*)p + 1) = make_float4(a[4],a[5],a[6],a[7]);
}

// decode 8 bf16 (uint4), apply LN+relu, re-encode
__device__ __forceinline__ uint4 lnrelu_pack(uint4 r, float mean, float rstd){
    float f0 = __uint_as_float(r.x << 16), f1 = __uint_as_float(r.x & 0xffff0000u);
    float f2 = __uint_as_float(r.y << 16), f3 = __uint_as_float(r.y & 0xffff0000u);
    float f4 = __uint_as_float(r.z << 16), f5 = __uint_as_float(r.z & 0xffff0000u);
    float f6 = __uint_as_float(r.w << 16), f7 = __uint_as_float(r.w & 0xffff0000u);
    f0 = fmaxf(0.f,(f0-mean)*rstd); f1 = fmaxf(0.f,(f1-mean)*rstd);
    f2 = fmaxf(0.f,(f2-mean)*rstd); f3 = fmaxf(0.f,(f3-mean)*rstd);
    f4 = fmaxf(0.f,(f4-mean)*rstd); f5 = fmaxf(0.f,(f5-mean)*rstd);
    f6 = fmaxf(0.f,(f6-mean)*rstd); f7 = fmaxf(0.f,(f7-mean)*rstd);
    uint4 q;
    q.x = f2bu(f0) | (f2bu(f1) << 16);
    q.y = f2bu(f2) | (f2bu(f3) << 16);
    q.z = f2bu(f4) | (f2bu(f5) << 16);
    q.w = f2bu(f6) | (f2bu(f7) << 16);
    return q;
}
__device__ __forceinline__ uint4 pack8f(float4 a, float4 b){
    uint4 q;
    q.x = f2bu(a.x) | (f2bu(a.y) << 16);
    q.y = f2bu(a.z) | (f2bu(a.w) << 16);
    q.z = f2bu(b.x) | (f2bu(b.y) << 16);
    q.w = f2bu(b.z) | (f2bu(b.w) << 16);
    return q;
}

// per-wave f64 pair reduce + 1-barrier block combine (LDS: 8 doubles)
__device__ __forceinline__ void block_red2(double ls, double ls2, double* sredw,
                                           int tx, double* redp, int bid)
{
    #pragma unroll
    for (int off = 32; off; off >>= 1) {
        ls  += __shfl_down(ls,  off, 64);
        ls2 += __shfl_down(ls2, off, 64);
    }
    const int w = tx >> 6, l = tx & 63;
    if (l == 0) { sredw[2*w] = ls; sredw[2*w+1] = ls2; }
    __syncthreads();
    if (tx == 0) {
        redp[2*(size_t)bid]     = ((sredw[0]+sredw[2])+(sredw[4]+sredw[6]));
        redp[2*(size_t)bid + 1] = ((sredw[1]+sredw[3])+(sredw[5]+sredw[7]));
    }
}

// ---------------- weight prep ----------------
__global__ void wt_transpose(const float* __restrict__ src, float* __restrict__ dst,
                             int O, int C) {
    int i = blockIdx.x*256 + threadIdx.x;
    if (i >= O*C) return;
    int o = i / C, c = i - o*C;
    dst[c*O + o] = src[i];
}

// KE1 [256][384] -> folded bf16 [256 o][256 k] (row==col==iInd)
__global__ void wt_ke1_bf(const float* __restrict__ src, bf16* __restrict__ dst) {
    int i = blockIdx.x*256 + threadIdx.x;
    if (i >= 256*256) return;
    int o = i >> 8, c = i & 255;
    float v;
    if (c < 128) v = src[o*384 + c] + src[o*384 + 128 + c];
    else         v = src[o*384 + 128 + c];
    dst[i] = f2b(v);
}

__global__ void wt_cast_bf(const float* __restrict__ src, bf16* __restrict__ dst, int cnt) {
    int i = blockIdx.x*256 + threadIdx.x;
    if (i < cnt) dst[i] = f2b(src[i]);
}

// ---------------- CSR build ----------------
__global__ void csr_hist(const int* __restrict__ ind, int* __restrict__ cnt, int E){
    int e = blockIdx.x*256 + threadIdx.x;
    if (e < E) atomicAdd(&cnt[ind[e]], 1);
}

__global__ void csr_scan(const int* __restrict__ cnt, int* __restrict__ rowptr,
                         int* __restrict__ cursor, int Nn)
{
    __shared__ int part[256];
    int tx = threadIdx.x;
    int chunk = (Nn + 255) / 256;
    int a0 = tx * chunk;
    int a1 = a0 + chunk; if (a1 > Nn) a1 = Nn; if (a0 > Nn) a0 = Nn;
    int s = 0;
    for (int i = a0; i < a1; ++i) s += cnt[i];
    part[tx] = s;
    __syncthreads();
    for (int d = 1; d < 256; d <<= 1) {
        int v = (tx >= d) ? part[tx - d] : 0;
        __syncthreads();
        part[tx] += v;
        __syncthreads();
    }
    int run = (tx == 0) ? 0 : part[tx - 1];
    for (int i = a0; i < a1; ++i) {
        rowptr[i] = run; cursor[i] = run;
        run += cnt[i];
    }
    if (tx == 255) rowptr[Nn] = run;
}

__global__ void csr_fill(const int* __restrict__ ind, int* __restrict__ cursor,
                         int* __restrict__ eadj, int E){
    int e = blockIdx.x*256 + threadIdx.x;
    if (e < E) {
        int p = atomicAdd(&cursor[ind[e]], 1);
        eadj[p] = e;
    }
}

// -------- gather: s[:,node] = sum_{e in adj(node)} y[:,e]; y bf16 [E][128] ----
__launch_bounds__(256)
__global__ void gather_nodes(const bf16* __restrict__ y,
                             const int* __restrict__ rowptr,
                             const int* __restrict__ eadj,
                             float* __restrict__ s, int Nn)
{
    int wid  = threadIdx.x >> 6;
    int lane = threadIdx.x & 63;
    int node = blockIdx.x * 4 + wid;
    if (node >= Nn) return;
    int k0 = rowptr[node], k1 = rowptr[node+1];
    const unsigned* yu = (const unsigned*)y;
    float a0=0.f,a1=0.f,b0=0.f,b1=0.f,c0=0.f,c1=0.f,d0=0.f,d1=0.f;
    int k = k0;
    for (; k + 4 <= k1; k += 4) {
        int e0 = eadj[k], e1 = eadj[k+1], e2 = eadj[k+2], e3 = eadj[k+3];
        unsigned v0 = yu[(size_t)e0*64 + lane];
        unsigned v1 = yu[(size_t)e1*64 + lane];
        unsigned v2 = yu[(size_t)e2*64 + lane];
        unsigned v3 = yu[(size_t)e3*64 + lane];
        a0 += __uint_as_float(v0 << 16); a1 += __uint_as_float(v0 & 0xffff0000u);
        b0 += __uint_as_float(v1 << 16); b1 += __uint_as_float(v1 & 0xffff0000u);
        c0 += __uint_as_float(v2 << 16); c1 += __uint_as_float(v2 & 0xffff0000u);
        d0 += __uint_as_float(v3 << 16); d1 += __uint_as_float(v3 & 0xffff0000u);
    }
    for (; k < k1; ++k) {
        unsigned v = yu[(size_t)eadj[k]*64 + lane];
        a0 += __uint_as_float(v << 16); a1 += __uint_as_float(v & 0xffff0000u);
    }
    a0 += (b0 + c0) + d0;
    a1 += (b1 + c1) + d1;
    *(float2*)(s + (size_t)node*128 + lane*2) = make_float2(a0, a1);
}

// ---------------- LN stat reduction ----------------
__global__ void ln_reduce(const double* __restrict__ redp, int nb,
                          float* __restrict__ ln, double cnt)
{
    __shared__ double s0[256], s1[256];
    int tx = threadIdx.x;
    double a = 0.0, b = 0.0;
    for (int i = tx; i < nb; i += 256) { a += redp[2*i]; b += redp[2*i+1]; }
    s0[tx] = a; s1[tx] = b;
    __syncthreads();
    for (int s = 128; s > 0; s >>= 1) {
        if (tx < s) { s0[tx] += s0[tx+s]; s1[tx] += s1[tx+s]; }
        __syncthreads();
    }
    if (tx == 0) {
        double m = s0[0] / cnt;
        double var = s1[0] / cnt - m*m;
        if (var < 0.0) var = 0.0;
        ln[0] = (float)m;
        ln[1] = (float)(1.0 / sqrt(var + 1e-5));
    }
}

// ============ MFMA GEMM1 edge: u[E][256] = W1[256x256] @ [xnb(iInd); xe] =====
__launch_bounds__(256)
__global__ void mfma_mm1_edge(const bf16* __restrict__ Wb,   // [256 o][256 k]
                              const bf16* __restrict__ xnb,  // [N][128] bf16
                              const float* __restrict__ xe,  // [E][128] f32 cm
                              const int* __restrict__ iInd,
                              bf16* __restrict__ ucm,        // [E][256] bf16
                              int E, double* __restrict__ redp)
{
    __shared__ __align__(16) unsigned short Vs[64*256];
    __shared__ double sredw[8];
    const int tx = threadIdx.x;
    const int x0 = blockIdx.x * 64;
    const int e = tx >> 2, q4 = tx & 3;
    const int xedge = x0 + e;
    const bool ev = xedge < E;
    const int gidx = ev ? iInd[xedge] : 0;
    const unsigned swz = (unsigned)((e & 7) << 3);

    // node part k=0..127 (bf16 gather; lane-quads contiguous 64B)
    #pragma unroll
    for (int p = 0; p < 4; ++p) {
        int k0 = q4*8 + p*32;
        uint4 v = make_uint4(0,0,0,0);
        if (ev) v = *(const uint4*)(xnb + (size_t)gidx*128 + k0);
        *(uint4*)&Vs[(unsigned)(e*256 + k0) ^ swz] = v;
    }
    // edge part k=128..255 (f32 cm -> bf16)
    #pragma unroll
    for (int p = 0; p < 4; ++p) {
        int k0 = q4*8 + p*32;
        uint4 v = make_uint4(0,0,0,0);
        if (ev) {
            const float* s = xe + (size_t)xedge*128 + k0;
            v = pack8f(*(const float4*)s, *(const float4*)(s + 4));
        }
        *(uint4*)&Vs[(unsigned)(e*256 + 128 + k0) ^ swz] = v;
    }
    __syncthreads();

    const int w = tx >> 6, l = tx & 63;
    const int colb = l & 15, grp = l >> 4;
    f32x4 acc[4][4];
    #pragma unroll
    for (int m=0;m<4;++m)
        #pragma unroll
        for (int n=0;n<4;++n) acc[m][n] = (f32x4){0.f,0.f,0.f,0.f};

    const bf16* wp = Wb + (size_t)(w*64 + colb)*256 + grp*8;
    bf16x8 aC[4], aN[4];
    #pragma unroll
    for (int m=0;m<4;++m)
        aC[m] = __builtin_bit_cast(bf16x8, *(const uint4*)(wp + m*16*256));

    #pragma unroll
    for (int kc = 0; kc < 8; ++kc) {
        const int kf = kc*32 + grp*8;
        if (kc < 7) {
            #pragma unroll
            for (int m=0;m<4;++m)
                aN[m] = __builtin_bit_cast(bf16x8,
                          *(const uint4*)(wp + m*16*256 + (kc+1)*32));
        }
        bf16x8 b[4];
        #pragma unroll
        for (int n=0;n<4;++n) {
            int ee = n*16 + colb;
            b[n] = __builtin_bit_cast(bf16x8,
                     *(const uint4*)&Vs[(unsigned)(ee*256 + kf) ^ (unsigned)((ee&7)<<3)]);
        }
        #pragma unroll
        for (int m=0;m<4;++m)
            #pragma unroll
            for (int n=0;n<4;++n)
                acc[m][n] = __builtin_amdgcn_mfma_f32_16x16x32_bf16(aC[m], b[n], acc[m][n], 0, 0, 0);
        #pragma unroll
        for (int m=0;m<4;++m) aC[m] = aN[m];
    }

    // ---- LN partials from acc (guarded), then u through LDS (streaming) ----
    double ls = 0.0, ls2 = 0.0;
    #pragma unroll
    for (int n=0;n<4;++n) {
        int edge = x0 + n*16 + colb;
        if (edge < E) {
            #pragma unroll
            for (int m=0;m<4;++m) {
                f32x4 v = acc[m][n];
                ls  += (double)v[0] + (double)v[1] + (double)v[2] + (double)v[3];
                ls2 += (double)v[0]*v[0] + (double)v[1]*v[1]
                     + (double)v[2]*v[2] + (double)v[3]*v[3];
            }
        }
    }

    __syncthreads();  // all B-reads done; reuse Vs for output transpose
    const int rq = grp*4;
    #pragma unroll
    for (int n=0;n<4;++n) {
        int ee = n*16 + colb;
        #pragma unroll
        for (int m=0;m<4;++m) {
            f32x4 v = acc[m][n];
            int r0 = w*64 + m*16 + rq;
            uint2 q;
            q.x = f2bu(v[0]) | (f2bu(v[1]) << 16);
            q.y = f2bu(v[2]) | (f2bu(v[3]) << 16);
            *(uint2*)&Vs[(unsigned)(ee*256 + r0) ^ (unsigned)((ee&7)<<3)] = q;
        }
    }
    __syncthreads();
    if (ev) {
        #pragma unroll
        for (int p = 0; p < 8; ++p) {
            int c0 = q4*8 + p*32;
            uint4 v = *(uint4*)&Vs[(unsigned)(e*256 + c0) ^ swz];
            *(uint4*)(ucm + (size_t)xedge*256 + c0) = v;
        }
    }
    block_red2(ls, ls2, sredw, tx, redp, blockIdx.x);
}

// ============ MFMA GEMM1 node: u[N][256] = KN1[256x384] @ [ave; div; xn] =====
__launch_bounds__(256)
__global__ void mfma_mm1_node(const bf16* __restrict__ Wb,   // [256 o][384 k]
                              const float* __restrict__ si,  // [N][128] f32 cm
                              const float* __restrict__ sj,
                              const float* __restrict__ xn,  // [N][128] f32 cm
                              bf16* __restrict__ ucm,        // [N][256] bf16
                              int Nn, double* __restrict__ redp)
{
    __shared__ __align__(16) unsigned short Vs[64*384];
    __shared__ double sredw[8];
    const int tx = threadIdx.x;
    const int x0 = blockIdx.x * 64;
    const int e = tx >> 2, q4 = tx & 3;
    const int node = x0 + e;
    const bool nv = node < Nn;
    const unsigned swz = (unsigned)((e & 7) << 3);

    #pragma unroll
    for (int p = 0; p < 4; ++p) {
        int k0 = q4*8 + p*32;
        uint4 va = make_uint4(0,0,0,0), vd = va;
        if (nv) {
            const float* ps = si + (size_t)node*128 + k0;
            const float* pt = sj + (size_t)node*128 + k0;
            float4 a0 = *(const float4*)ps, a1 = *(const float4*)(ps+4);
            float4 b0 = *(const float4*)pt, b1 = *(const float4*)(pt+4);
            float4 av0 = make_float4(0.5f*(a0.x+b0.x),0.5f*(a0.y+b0.y),
                                     0.5f*(a0.z+b0.z),0.5f*(a0.w+b0.w));
            float4 av1 = make_float4(0.5f*(a1.x+b1.x),0.5f*(a1.y+b1.y),
                                     0.5f*(a1.z+b1.z),0.5f*(a1.w+b1.w));
            float4 dv0 = make_float4(a0.x-b0.x,a0.y-b0.y,a0.z-b0.z,a0.w-b0.w);
            float4 dv1 = make_float4(a1.x-b1.x,a1.y-b1.y,a1.z-b1.z,a1.w-b1.w);
            va = pack8f(av0, av1);
            vd = pack8f(dv0, dv1);
        }
        *(uint4*)&Vs[(unsigned)(e*384 + k0) ^ swz] = va;
        *(uint4*)&Vs[(unsigned)(e*384 + 128 + k0) ^ swz] = vd;
    }
    #pragma unroll
    for (int p = 0; p < 4; ++p) {
        int k0 = q4*8 + p*32;
        uint4 v = make_uint4(0,0,0,0);
        if (nv) {
            const float* s = xn + (size_t)node*128 + k0;
            v = pack8f(*(const float4*)s, *(const float4*)(s + 4));
        }
        *(uint4*)&Vs[(unsigned)(e*384 + 256 + k0) ^ swz] = v;
    }
    __syncthreads();

    const int w = tx >> 6, l = tx & 63;
    const int colb = l & 15, grp = l >> 4;
    f32x4 acc[4][4];
    #pragma unroll
    for (int m=0;m<4;++m)
        #pragma unroll
        for (int n=0;n<4;++n) acc[m][n] = (f32x4){0.f,0.f,0.f,0.f};

    const bf16* wp = Wb + (size_t)(w*64 + colb)*384 + grp*8;
    bf16x8 aC[4], aN[4];
    #pragma unroll
    for (int m=0;m<4;++m)
        aC[m] = __builtin_bit_cast(bf16x8, *(const uint4*)(wp + m*16*384));

    #pragma unroll
    for (int kc = 0; kc < 12; ++kc) {
        const int kf = kc*32 + grp*8;
        if (kc < 11) {
            #pragma unroll
            for (int m=0;m<4;++m)
                aN[m] = __builtin_bit_cast(bf16x8,
                          *(const uint4*)(wp + m*16*384 + (kc+1)*32));
        }
        bf16x8 b[4];
        #pragma unroll
        for (int n=0;n<4;++n) {
            int ee = n*16 + colb;
            b[n] = __builtin_bit_cast(bf16x8,
                     *(const uint4*)&Vs[(unsigned)(ee*384 + kf) ^ (unsigned)((ee&7)<<3)]);
        }
        #pragma unroll
        for (int m=0;m<4;++m)
            #pragma unroll
            for (int n=0;n<4;++n)
                acc[m][n] = __builtin_amdgcn_mfma_f32_16x16x32_bf16(aC[m], b[n], acc[m][n], 0, 0, 0);
        #pragma unroll
        for (int m=0;m<4;++m) aC[m] = aN[m];
    }

    double ls = 0.0, ls2 = 0.0;
    const int rq = grp*4;
    #pragma unroll
    for (int n=0;n<4;++n) {
        int nd = x0 + n*16 + colb;
        if (nd < Nn) {
            #pragma unroll
            for (int m=0;m<4;++m) {
                f32x4 v = acc[m][n];
                int r0 = w*64 + m*16 + rq;
                uint2 q;
                q.x = f2bu(v[0]) | (f2bu(v[1]) << 16);
                q.y = f2bu(v[2]) | (f2bu(v[3]) << 16);
                *(uint2*)(ucm + (size_t)nd*256 + r0) = q;
                ls  += (double)v[0] + (double)v[1] + (double)v[2] + (double)v[3];
                ls2 += (double)v[0]*v[0] + (double)v[1]*v[1]
                     + (double)v[2]*v[2] + (double)v[3]*v[3];
            }
        }
    }
    block_red2(ls, ls2, sredw, tx, redp, blockIdx.x);
}

// ============ MFMA GEMM2 (OC=128): y = W2 @ relu(LN(u)); fused epilogues =====
enum { E2_EDGE = 0, E2_NODE = 1, E2_XE0 = 2, E2_XN0 = 3 };

template<int IC, int EPI>
__launch_bounds__(256)
__global__ void mfma_mm2(const bf16* __restrict__ Wb2,  // [128 o][IC k]
                         const bf16* __restrict__ ucm,  // [n][IC] bf16
                         const float* __restrict__ ln,
                         float* __restrict__ dst,       // xe or xn, [n][128] f32 cm
                         bf16* __restrict__ yv,         // y [E][128] bf16 (EDGE)
                         bf16* __restrict__ xnb,        // xn shadow (NODE/XN0)
                         int n)
{
    __shared__ __align__(16) unsigned short Vs[64*IC];
    const int tx = threadIdx.x;
    const int x0 = blockIdx.x * 64;
    const int e = tx >> 2, q4 = tx & 3;
    const int row = x0 + e;
    const bool rv = row < n;
    const float mean = ln[0], rstd = ln[1];
    const unsigned swz = (unsigned)((e & 7) << 3);

    #pragma unroll
    for (int p = 0; p < IC/32; ++p) {
        int k0 = q4*8 + p*32;
        uint4 v = make_uint4(0,0,0,0);
        if (rv) {
            uint4 r = *(const uint4*)(ucm + (size_t)row*IC + k0);
            v = lnrelu_pack(r, mean, rstd);
        }
        *(uint4*)&Vs[(unsigned)(e*IC + k0) ^ swz] = v;
    }
    __syncthreads();

    const int w = tx >> 6, l = tx & 63;
    const int colb = l & 15, grp = l >> 4;
    f32x4 acc[2][4];
    #pragma unroll
    for (int m=0;m<2;++m)
        #pragma unroll
        for (int nn=0;nn<4;++nn) acc[m][nn] = (f32x4){0.f,0.f,0.f,0.f};

    const bf16* wp = Wb2 + (size_t)(w*32 + colb)*IC + grp*8;
    bf16x8 aC[2], aN[2];
    #pragma unroll
    for (int m=0;m<2;++m)
        aC[m] = __builtin_bit_cast(bf16x8, *(const uint4*)(wp + m*16*IC));

    #pragma unroll
    for (int kc = 0; kc < IC/32; ++kc) {
        const int kf = kc*32 + grp*8;
        if (kc < IC/32 - 1) {
            #pragma unroll
            for (int m=0;m<2;++m)
                aN[m] = __builtin_bit_cast(bf16x8,
                          *(const uint4*)(wp + m*16*IC + (kc+1)*32));
        }
        bf16x8 b[4];
        #pragma unroll
        for (int nn=0;nn<4;++nn) {
            int ee = nn*16 + colb;
            b[nn] = __builtin_bit_cast(bf16x8,
                     *(const uint4*)&Vs[(unsigned)(ee*IC + kf) ^ (unsigned)((ee&7)<<3)]);
        }
        #pragma unroll
        for (int m=0;m<2;++m)
            #pragma unroll
            for (int nn=0;nn<4;++nn)
                acc[m][nn] = __builtin_amdgcn_mfma_f32_16x16x32_bf16(aC[m], b[nn], acc[m][nn], 0, 0, 0);
        #pragma unroll
        for (int m=0;m<2;++m) aC[m] = aN[m];
    }

    const int rq = grp*4;
    #pragma unroll
    for (int nn=0;nn<4;++nn) {
        int x = x0 + nn*16 + colb;
        if (x < n) {
            #pragma unroll
            for (int m=0;m<2;++m) {
                f32x4 v = acc[m][nn];
                int r0 = w*32 + m*16 + rq;
                if constexpr (EPI == E2_EDGE) {
                    uint2 q;
                    q.x = f2bu(v[0]) | (f2bu(v[1]) << 16);
                    q.y = f2bu(v[2]) | (f2bu(v[3]) << 16);
                    *(uint2*)(yv + (size_t)x*128 + r0) = q;
                    float* px = dst + (size_t)x*128 + r0;
                    float4 o = *(float4*)px;
                    o.x += HSTEP*v[0]; o.y += HSTEP*v[1];
                    o.z += HSTEP*v[2]; o.w += HSTEP*v[3];
                    *(float4*)px = o;
                } else if constexpr (EPI == E2_XE0) {
                    *(float4*)(dst + (size_t)x*128 + r0) =
                        make_float4(v[0], v[1], v[2], v[3]);
                } else if constexpr (EPI == E2_NODE) {
                    float* px = dst + (size_t)x*128 + r0;
                    float4 o = *(float4*)px;
                    o.x += HSTEP*v[0]; o.y += HSTEP*v[1];
                    o.z += HSTEP*v[2]; o.w += HSTEP*v[3];
                    *(float4*)px = o;
                    uint2 q;
                    q.x = f2bu(o.x) | (f2bu(o.y) << 16);
                    q.y = f2bu(o.z) | (f2bu(o.w) << 16);
                    *(uint2*)(xnb + (size_t)x*128 + r0) = q;
                } else {  // E2_XN0
                    *(float4*)(dst + (size_t)x*128 + r0) =
                        make_float4(v[0], v[1], v[2], v[3]);
                    uint2 q;
                    q.x = f2bu(v[0]) | (f2bu(v[1]) << 16);
                    q.y = f2bu(v[2]) | (f2bu(v[3]) << 16);
                    *(uint2*)(xnb + (size_t)x*128 + r0) = q;
                }
            }
        }
    }
}

// ---------------- opening GEMM1 (VALU, IC=32): u[n][128] bf16 cm --------------
__launch_bounds__(256)
__global__ void mm1_open(const float* __restrict__ Wt,   // [32][128]
                         const float* __restrict__ xin,  // [32][n] f32 rm
                         bf16* __restrict__ ucm,         // [n][128] bf16
                         int n, double* __restrict__ redp)
{
    __shared__ float lv[32][64];
    __shared__ double sredw[8];
    const int tx = threadIdx.x;
    const int tr = tx & 31, tc = tx >> 5;
    const int x0 = blockIdx.x * 64;

    float acc[4][8];
    #pragma unroll
    for (int ri=0; ri<4; ++ri)
        #pragma unroll
        for (int ei=0; ei<8; ++ei) acc[ri][ei] = 0.f;

    #pragma unroll
    for (int k=0; k<2; ++k) {
        int id = k*256 + tx;
        int xq = id & 15, cc = id >> 4;
        int x = x0 + xq*4;
        const float* p = xin + (size_t)cc*n + x;
        float4 q;
        if (x + 3 < n) q = *(const float4*)p;
        else {
            q.x = (x  <n)?p[0]:0.f; q.y = (x+1<n)?p[1]:0.f;
            q.z = (x+2<n)?p[2]:0.f; q.w = (x+3<n)?p[3]:0.f;
        }
        *(float4*)&lv[cc][xq*4] = q;
    }
    __syncthreads();
    for (int cc=0; cc<32; ++cc) {
        const float* wrow = Wt + cc*128 + tr*4;
        float w[4] = {wrow[0], wrow[1], wrow[2], wrow[3]};
        float vv[8];
        #pragma unroll
        for (int ei=0; ei<8; ++ei) vv[ei] = lv[cc][tc*8+ei];
        #pragma unroll
        for (int ri=0; ri<4; ++ri)
            #pragma unroll
            for (int ei=0; ei<8; ++ei)
                acc[ri][ei] = fmaf(w[ri], vv[ei], acc[ri][ei]);
    }

    double ls = 0.0, ls2 = 0.0;
    #pragma unroll
    for (int ei=0; ei<8; ++ei) {
        int x = x0 + tc*8 + ei;
        if (x < n) {
            uint2 bq;
            bq.x = f2bu(acc[0][ei]) | (f2bu(acc[1][ei]) << 16);
            bq.y = f2bu(acc[2][ei]) | (f2bu(acc[3][ei]) << 16);
            *(uint2*)(ucm + (size_t)x*128 + tr*4) = bq;
            #pragma unroll
            for (int ri=0; ri<4; ++ri) {
                double y = acc[ri][ei]; ls += y; ls2 += y*y;
            }
        }
    }
    block_red2(ls, ls2, sredw, tx, redp, blockIdx.x);
}

// ---------------- final: out[64][N] = KNout @ xn (VALU) ----------------
__launch_bounds__(256)
__global__ void final_out(const float* __restrict__ Wt,   // [128 c][64 o]
                          const float* __restrict__ xncm, // [N][128] f32
                          float* __restrict__ out, int n)
{
    __shared__ float lv[32][64];
    const int tx = threadIdx.x;
    const int tr = tx & 31, tc = tx >> 5;
    const int x0 = blockIdx.x * 64;

    float acc[2][8];
    #pragma unroll
    for (int ri=0; ri<2; ++ri)
        #pragma unroll
        for (int ei=0; ei<8; ++ei) acc[ri][ei] = 0.f;

    for (int c0 = 0; c0 < 128; c0 += 32) {
        #pragma unroll
        for (int k=0; k<2; ++k) {
            int id = k*256 + tx;
            int xx = id & 63, cg = id >> 6;
            int x = x0 + xx;
            float4 q;
            if (x < n) q = *(const float4*)(xncm + (size_t)x*128 + c0 + cg*4);
            else { q.x=q.y=q.z=q.w=0.f; }
            lv[cg*4+0][xx]=q.x; lv[cg*4+1][xx]=q.y;
            lv[cg*4+2][xx]=q.z; lv[cg*4+3][xx]=q.w;
        }
        __syncthreads();
        for (int cc=0; cc<32; ++cc) {
            const float* wrow = Wt + (c0+cc)*64 + tr*2;
            float w0 = wrow[0], w1 = wrow[1];
            float vv[8];
            #pragma unroll
            for (int ei=0; ei<8; ++ei) vv[ei] = lv[cc][tc*8+ei];
            #pragma unroll
            for (int ei=0; ei<8; ++ei) {
                acc[0][ei] = fmaf(w0, vv[ei], acc[0][ei]);
                acc[1][ei] = fmaf(w1, vv[ei], acc[1][ei]);
            }
        }
        __syncthreads();
    }

    const bool full = (x0 + 64 <= n);
    #pragma unroll
    for (int ri=0; ri<2; ++ri) {
        int r = tr*2 + ri;
        if (full) {
            store8(out + (size_t)r*n + x0 + tc*8, acc[ri]);
        } else {
            #pragma unroll
            for (int ei=0; ei<8; ++ei) {
                int x = x0 + tc*8 + ei;
                if (x < n) out[(size_t)r*n + x] = acc[ri][ei];
            }
        }
    }
}

// ---------------- xe col-major -> row-major f32 output ----------------
__launch_bounds__(256)
__global__ void xe_transpose(const float* __restrict__ xe, float* __restrict__ out, int E)
{
    __shared__ float T[128][65];
    const int tx = threadIdx.x;
    const int x0 = blockIdx.x * 64;
    const int es = tx & 63, cg = tx >> 6;
    #pragma unroll
    for (int p = 0; p < 8; ++p) {
        int c = cg*4 + p*16;
        if (x0 + es < E) {
            float4 v = *(const float4*)(xe + (size_t)(x0+es)*128 + c);
            T[c+0][es] = v.x; T[c+1][es] = v.y; T[c+2][es] = v.z; T[c+3][es] = v.w;
        }
    }
    __syncthreads();
    const int c2 = tx >> 1, eo = (tx & 1)*32;
    if (x0 + 64 <= E) {
        #pragma unroll
        for (int q = 0; q < 8; ++q) {
            float4 v = make_float4(T[c2][eo+q*4], T[c2][eo+q*4+1],
                                   T[c2][eo+q*4+2], T[c2][eo+q*4+3]);
            *(float4*)(out + (size_t)c2*E + x0 + eo + q*4) = v;
        }
    } else {
        for (int q = 0; q < 32; ++q) {
            int x = x0 + eo + q;
            if (x < E) out[(size_t)c2*E + x] = T[c2][eo+q];
        }
    }
}

extern "C" void kernel_launch(void* const* d_in, const int* in_sizes, int n_in,
                              void* d_out, int out_size, void* d_ws, size_t ws_size,
                              hipStream_t stream)
{
    const int N = in_sizes[0] / 32;          // 50000
    const int E = in_sizes[1] / 32;          // 500000
    const int NL = in_sizes[9] / (256*384);  // 4

    const float* xn_in = (const float*)d_in[0];
    const float* xe_in = (const float*)d_in[1];
    const int*   iInd  = (const int*)d_in[2];
    const int*   jInd  = (const int*)d_in[3];
    const float* K1N = (const float*)d_in[4];
    const float* K2N = (const float*)d_in[5];
    const float* K1E = (const float*)d_in[6];
    const float* K2E = (const float*)d_in[7];
    const float* KNo = (const float*)d_in[8];
    const float* KE1 = (const float*)d_in[9];
    const float* KE2 = (const float*)d_in[10];
    const float* KN1 = (const float*)d_in[11];
    const float* KN2 = (const float*)d_in[12];

    char* base = (char*)d_ws;
    size_t off = 0;
    auto carve = [&](size_t bytes)->void* {
        void* p = base + off; off += (bytes + 255) & ~(size_t)255; return p;
    };
    float* xn  = (float*)carve((size_t)128*N*sizeof(float));  // [N][128] cm
    float* xe  = (float*)carve((size_t)128*E*sizeof(float));  // [E][128] cm
    bf16*  u   = (bf16*) carve((size_t)256*E*sizeof(bf16));   // [n][IC] cm bf16
    bf16*  y   = (bf16*) carve((size_t)128*E*sizeof(bf16));   // [E][128] bf16
    float* si  = (float*)carve((size_t)128*N*sizeof(float));
    float* sj  = (float*)carve((size_t)128*N*sizeof(float));
    float* wtsf= (float*)carve((32*128*2 + 128*64)*sizeof(float));
    bf16*  Wb   = (bf16*)carve((size_t)256*256*sizeof(bf16)); // folded KE1
    bf16*  Wb2  = (bf16*)carve((size_t)128*256*sizeof(bf16)); // KE2
    bf16*  Wn1b = (bf16*)carve((size_t)256*384*sizeof(bf16)); // KN1
    bf16*  Wn2b = (bf16*)carve((size_t)128*256*sizeof(bf16)); // KN2
    bf16*  K2Nb = (bf16*)carve((size_t)128*128*sizeof(bf16));
    bf16*  K2Eb = (bf16*)carve((size_t)128*128*sizeof(bf16));
    bf16*  xnb  = (bf16*)carve((size_t)128*N*sizeof(bf16));   // xn shadow
    double* redp = (double*)carve(2*8192*sizeof(double));
    float* lnp = (float*)carve(256);
    int* cnt      = (int*)carve((size_t)N*sizeof(int));
    int* rowptr_i = (int*)carve((size_t)(N+1)*sizeof(int));
    int* rowptr_j = (int*)carve((size_t)(N+1)*sizeof(int));
    int* cur_i    = (int*)carve((size_t)N*sizeof(int));
    int* cur_j    = (int*)carve((size_t)N*sizeof(int));
    int* eadj_i   = (int*)carve((size_t)E*sizeof(int));
    int* eadj_j   = (int*)carve((size_t)E*sizeof(int));

    if (ws_size < off) return;

    float* K1Nt = wtsf;                // [32][128]
    float* K1Et = K1Nt + 32*128;       // [32][128]
    float* KNoT = K1Et + 32*128;       // [128][64]

    wt_transpose<<<dim3((128*32 +255)/256),dim3(256),0,stream>>>(K1N, K1Nt, 128, 32);
    wt_transpose<<<dim3((128*32 +255)/256),dim3(256),0,stream>>>(K1E, K1Et, 128, 32);
    wt_transpose<<<dim3((64*128 +255)/256),dim3(256),0,stream>>>(KNo, KNoT, 64, 128);
    wt_cast_bf<<<dim3(64),dim3(256),0,stream>>>(K2N, K2Nb, 128*128);
    wt_cast_bf<<<dim3(64),dim3(256),0,stream>>>(K2E, K2Eb, 128*128);

    const int gN = (N + 63)/64, gE = (E + 63)/64;
    const int gEb = (E + 255)/256;

    // CSR build once
    (void)hipMemsetAsync(cnt, 0, (size_t)N*sizeof(int), stream);
    csr_hist<<<gEb,256,0,stream>>>(iInd, cnt, E);
    csr_scan<<<1,256,0,stream>>>(cnt, rowptr_i, cur_i, N);
    csr_fill<<<gEb,256,0,stream>>>(iInd, cur_i, eadj_i, E);
    (void)hipMemsetAsync(cnt, 0, (size_t)N*sizeof(int), stream);
    csr_hist<<<gEb,256,0,stream>>>(jInd, cnt, E);
    csr_scan<<<1,256,0,stream>>>(cnt, rowptr_j, cur_j, N);
    csr_fill<<<gEb,256,0,stream>>>(jInd, cur_j, eadj_j, E);

    // ---- opening: nodes ----
    mm1_open<<<gN,256,0,stream>>>(K1Nt, xn_in, u, N, redp);
    ln_reduce<<<1,256,0,stream>>>(redp, gN, lnp, 128.0*N);
    mfma_mm2<128,E2_XN0><<<gN,256,0,stream>>>(K2Nb, u, lnp, xn, nullptr, xnb, N);

    // ---- opening: edges ----
    mm1_open<<<gE,256,0,stream>>>(K1Et, xe_in, u, E, redp);
    ln_reduce<<<1,256,0,stream>>>(redp, gE, lnp, 128.0*E);
    mfma_mm2<128,E2_XE0><<<gE,256,0,stream>>>(K2Eb, u, lnp, xe, nullptr, nullptr, E);

    for (int l = 0; l < NL; ++l) {
        wt_ke1_bf<<<dim3(256),dim3(256),0,stream>>>(KE1 + (size_t)l*256*384, Wb);
        wt_cast_bf<<<dim3(128),dim3(256),0,stream>>>(KE2 + (size_t)l*128*256, Wb2, 128*256);
        wt_cast_bf<<<dim3(384),dim3(256),0,stream>>>(KN1 + (size_t)l*256*384, Wn1b, 256*384);
        wt_cast_bf<<<dim3(128),dim3(256),0,stream>>>(KN2 + (size_t)l*128*256, Wn2b, 128*256);

        // edge double_layer (MFMA)
        mfma_mm1_edge<<<gE,256,0,stream>>>(Wb, xnb, xe, iInd, u, E, redp);
        ln_reduce<<<1,256,0,stream>>>(redp, gE, lnp, 256.0*E);
        mfma_mm2<256,E2_EDGE><<<gE,256,0,stream>>>(Wb2, u, lnp, xe, y, nullptr, E);
        gather_nodes<<<(N+3)/4,256,0,stream>>>(y, rowptr_i, eadj_i, si, N);
        gather_nodes<<<(N+3)/4,256,0,stream>>>(y, rowptr_j, eadj_j, sj, N);

        // node double_layer (MFMA)
        mfma_mm1_node<<<gN,256,0,stream>>>(Wn1b, si, sj, xn, u, N, redp);
        ln_reduce<<<1,256,0,stream>>>(redp, gN, lnp, 256.0*N);
        mfma_mm2<256,E2_NODE><<<gN,256,0,stream>>>(Wn2b, u, lnp, xn, nullptr, xnb, N);
    }

    // ---- final ----
    final_out<<<gN,256,0,stream>>>(KNoT, xn, (float*)d_out, N);
    xe_transpose<<<gE,256,0,stream>>>(xe, (float*)d_out + (size_t)64*N, E);
}

// Round 5
// 3563.350 us; speedup vs baseline: 3.3847x; 1.0268x over previous
//
#include <hip/hip_runtime.h>
#include <hip/hip_bf16.h>

// gNet: 4-layer graph net, B=1, HID=128, N=50000, E=500000.
// R1: scatter->CSR gather (atomics removed).
// R2: edge GEMMs on MFMA bf16; u col-major [E][256] bf16; xe col-major f32.
// R3: coalesced staging; node layer + opening mm2s on MFMA.
// R4: LN partials via wave shfl-reduce; y bf16; gather unrolled x4.
// R5: persistent 2-phase pipelined mm1_edge/mm2 (reg-stage next tile during
//     MFMA of current -- T14); xe bf16 shadow (xeb) for mm1_edge staging;
//     dropped R4's LDS output transpose (neutral, +3M bank conflicts).

typedef __hip_bfloat16 bf16;
typedef __attribute__((ext_vector_type(8))) short bf16x8;
typedef __attribute__((ext_vector_type(4))) float f32x4;

#define HSTEP 0.1f

__device__ __forceinline__ bf16  f2b(float v){ return __float2bfloat16(v); }
__device__ __forceinline__ unsigned int f2bu(float v){
    return (unsigned int)__builtin_bit_cast(unsigned short, __float2bfloat16(v));
}
__device__ __forceinline__ void store8(float* p, const float* a){
    *(float4*)p       = make_float4(a[0],a[1],a[2],a[3]);
    *((float4*)p + 1) = make_float4(a[4],a[5],a[6],a[7]);
}

// decode 8 bf16 (uint4), apply LN+relu, re-encode
__device__ __forceinline__ uint4 lnrelu_pack(uint4 r, float mean, float rstd){
    float f0 = __uint_as_float(r.x << 16), f1 = __uint_as_float(r.x & 0xffff0000u);
    float f2 = __uint_as_float(r.y << 16), f3 = __uint_as_float(r.y & 0xffff0000u);
    float f4 = __uint_as_float(r.z << 16), f5 = __uint_as_float(r.z & 0xffff0000u);
    float f6 = __uint_as_float(r.w << 16), f7 = __uint_as_float(r.w & 0xffff0000u);
    f0 = fmaxf(0.f,(f0-mean)*rstd); f1 = fmaxf(0.f,(f1-mean)*rstd);
    f2 = fmaxf(0.f,(f2-mean)*rstd); f3 = fmaxf(0.f,(f3-mean)*rstd);
    f4 = fmaxf(0.f,(f4-mean)*rstd); f5 = fmaxf(0.f,(f5-mean)*rstd);
    f6 = fmaxf(0.f,(f6-mean)*rstd); f7 = fmaxf(0.f,(f7-mean)*rstd);
    uint4 q;
    q.x = f2bu(f0) | (f2bu(f1) << 16);
    q.y = f2bu(f2) | (f2bu(f3) << 16);
    q.z = f2bu(f4) | (f2bu(f5) << 16);
    q.w = f2bu(f6) | (f2bu(f7) << 16);
    return q;
}
__device__ __forceinline__ uint4 pack8f(float4 a, float4 b){
    uint4 q;
    q.x = f2bu(a.x) | (f2bu(a.y) << 16);
    q.y = f2bu(a.z) | (f2bu(a.w) << 16);
    q.z = f2bu(b.x) | (f2bu(b.y) << 16);
    q.w = f2bu(b.z) | (f2bu(b.w) << 16);
    return q;
}

// per-wave f64 pair reduce + 1-barrier block combine (LDS: 8 doubles)
__device__ __forceinline__ void block_red2(double ls, double ls2, double* sredw,
                                           int tx, double* redp, int bid)
{
    #pragma unroll
    for (int off = 32; off; off >>= 1) {
        ls  += __shfl_down(ls,  off, 64);
        ls2 += __shfl_down(ls2, off, 64);
    }
    const int w = tx >> 6, l = tx & 63;
    if (l == 0) { sredw[2*w] = ls; sredw[2*w+1] = ls2; }
    __syncthreads();
    if (tx == 0) {
        redp[2*(size_t)bid]     = ((sredw[0]+sredw[2])+(sredw[4]+sredw[6]));
        redp[2*(size_t)bid + 1] = ((sredw[1]+sredw[3])+(sredw[5]+sredw[7]));
    }
}

// ---------------- weight prep ----------------
__global__ void wt_transpose(const float* __restrict__ src, float* __restrict__ dst,
                             int O, int C) {
    int i = blockIdx.x*256 + threadIdx.x;
    if (i >= O*C) return;
    int o = i / C, c = i - o*C;
    dst[c*O + o] = src[i];
}

// KE1 [256][384] -> folded bf16 [256 o][256 k] (row==col==iInd)
__global__ void wt_ke1_bf(const float* __restrict__ src, bf16* __restrict__ dst) {
    int i = blockIdx.x*256 + threadIdx.x;
    if (i >= 256*256) return;
    int o = i >> 8, c = i & 255;
    float v;
    if (c < 128) v = src[o*384 + c] + src[o*384 + 128 + c];
    else         v = src[o*384 + 128 + c];
    dst[i] = f2b(v);
}

__global__ void wt_cast_bf(const float* __restrict__ src, bf16* __restrict__ dst, int cnt) {
    int i = blockIdx.x*256 + threadIdx.x;
    if (i < cnt) dst[i] = f2b(src[i]);
}

// ---------------- CSR build ----------------
__global__ void csr_hist(const int* __restrict__ ind, int* __restrict__ cnt, int E){
    int e = blockIdx.x*256 + threadIdx.x;
    if (e < E) atomicAdd(&cnt[ind[e]], 1);
}

__global__ void csr_scan(const int* __restrict__ cnt, int* __restrict__ rowptr,
                         int* __restrict__ cursor, int Nn)
{
    __shared__ int part[256];
    int tx = threadIdx.x;
    int chunk = (Nn + 255) / 256;
    int a0 = tx * chunk;
    int a1 = a0 + chunk; if (a1 > Nn) a1 = Nn; if (a0 > Nn) a0 = Nn;
    int s = 0;
    for (int i = a0; i < a1; ++i) s += cnt[i];
    part[tx] = s;
    __syncthreads();
    for (int d = 1; d < 256; d <<= 1) {
        int v = (tx >= d) ? part[tx - d] : 0;
        __syncthreads();
        part[tx] += v;
        __syncthreads();
    }
    int run = (tx == 0) ? 0 : part[tx - 1];
    for (int i = a0; i < a1; ++i) {
        rowptr[i] = run; cursor[i] = run;
        run += cnt[i];
    }
    if (tx == 255) rowptr[Nn] = run;
}

__global__ void csr_fill(const int* __restrict__ ind, int* __restrict__ cursor,
                         int* __restrict__ eadj, int E){
    int e = blockIdx.x*256 + threadIdx.x;
    if (e < E) {
        int p = atomicAdd(&cursor[ind[e]], 1);
        eadj[p] = e;
    }
}

// -------- gather: s[:,node] = sum_{e in adj(node)} y[:,e]; y bf16 [E][128] ----
__launch_bounds__(256)
__global__ void gather_nodes(const bf16* __restrict__ y,
                             const int* __restrict__ rowptr,
                             const int* __restrict__ eadj,
                             float* __restrict__ s, int Nn)
{
    int wid  = threadIdx.x >> 6;
    int lane = threadIdx.x & 63;
    int node = blockIdx.x * 4 + wid;
    if (node >= Nn) return;
    int k0 = rowptr[node], k1 = rowptr[node+1];
    const unsigned* yu = (const unsigned*)y;
    float a0=0.f,a1=0.f,b0=0.f,b1=0.f,c0=0.f,c1=0.f,d0=0.f,d1=0.f;
    int k = k0;
    for (; k + 4 <= k1; k += 4) {
        int e0 = eadj[k], e1 = eadj[k+1], e2 = eadj[k+2], e3 = eadj[k+3];
        unsigned v0 = yu[(size_t)e0*64 + lane];
        unsigned v1 = yu[(size_t)e1*64 + lane];
        unsigned v2 = yu[(size_t)e2*64 + lane];
        unsigned v3 = yu[(size_t)e3*64 + lane];
        a0 += __uint_as_float(v0 << 16); a1 += __uint_as_float(v0 & 0xffff0000u);
        b0 += __uint_as_float(v1 << 16); b1 += __uint_as_float(v1 & 0xffff0000u);
        c0 += __uint_as_float(v2 << 16); c1 += __uint_as_float(v2 & 0xffff0000u);
        d0 += __uint_as_float(v3 << 16); d1 += __uint_as_float(v3 & 0xffff0000u);
    }
    for (; k < k1; ++k) {
        unsigned v = yu[(size_t)eadj[k]*64 + lane];
        a0 += __uint_as_float(v << 16); a1 += __uint_as_float(v & 0xffff0000u);
    }
    a0 += (b0 + c0) + d0;
    a1 += (b1 + c1) + d1;
    *(float2*)(s + (size_t)node*128 + lane*2) = make_float2(a0, a1);
}

// ---------------- LN stat reduction ----------------
__global__ void ln_reduce(const double* __restrict__ redp, int nb,
                          float* __restrict__ ln, double cnt)
{
    __shared__ double s0[256], s1[256];
    int tx = threadIdx.x;
    double a = 0.0, b = 0.0;
    for (int i = tx; i < nb; i += 256) { a += redp[2*i]; b += redp[2*i+1]; }
    s0[tx] = a; s1[tx] = b;
    __syncthreads();
    for (int s = 128; s > 0; s >>= 1) {
        if (tx < s) { s0[tx] += s0[tx+s]; s1[tx] += s1[tx+s]; }
        __syncthreads();
    }
    if (tx == 0) {
        double m = s0[0] / cnt;
        double var = s1[0] / cnt - m*m;
        if (var < 0.0) var = 0.0;
        ln[0] = (float)m;
        ln[1] = (float)(1.0 / sqrt(var + 1e-5));
    }
}

// ==== persistent, pipelined MFMA GEMM1 edge: u[E][256] = W1 @ [xnb(iInd); xeb]
__launch_bounds__(256)
__global__ void mfma_mm1_edge(const bf16* __restrict__ Wb,   // [256 o][256 k]
                              const bf16* __restrict__ xnb,  // [N][128] bf16
                              const bf16* __restrict__ xeb,  // [E][128] bf16
                              const int* __restrict__ iInd,
                              bf16* __restrict__ ucm,        // [E][256] bf16
                              int E, int ntiles, double* __restrict__ redp)
{
    __shared__ __align__(16) unsigned short Vs[64*256];
    __shared__ double sredw[8];
    const int tx = threadIdx.x;
    const int e = tx >> 2, q4 = tx & 3;
    const unsigned swz = (unsigned)((e & 7) << 3);
    const int w = tx >> 6, l = tx & 63;
    const int colb = l & 15, grp = l >> 4;

    uint4 rN[4] = {{0,0,0,0},{0,0,0,0},{0,0,0,0},{0,0,0,0}};
    uint4 rE[4] = {{0,0,0,0},{0,0,0,0},{0,0,0,0},{0,0,0,0}};

    auto issue = [&](int tt){
        int xedge = tt*64 + e;
        if (xedge < E) {
            int gidx = iInd[xedge];
            #pragma unroll
            for (int p=0;p<4;++p)
                rN[p] = *(const uint4*)(xnb + (size_t)gidx*128 + q4*8 + p*32);
            #pragma unroll
            for (int p=0;p<4;++p)
                rE[p] = *(const uint4*)(xeb + (size_t)xedge*128 + q4*8 + p*32);
        }
    };

    int t = blockIdx.x;
    if (t < ntiles) issue(t);
    double ls = 0.0, ls2 = 0.0;

    for (; t < ntiles; t += gridDim.x) {
        // stage tile t (vmcnt wait auto-inserted), then issue t+stride
        #pragma unroll
        for (int p=0;p<4;++p) {
            int k0 = q4*8 + p*32;
            *(uint4*)&Vs[(unsigned)(e*256 + k0) ^ swz] = rN[p];
            *(uint4*)&Vs[(unsigned)(e*256 + 128 + k0) ^ swz] = rE[p];
        }
        int tn = t + gridDim.x;
        if (tn < ntiles) issue(tn);
        __syncthreads();

        f32x4 acc[4][4];
        #pragma unroll
        for (int m=0;m<4;++m)
            #pragma unroll
            for (int n=0;n<4;++n) acc[m][n] = (f32x4){0.f,0.f,0.f,0.f};

        #pragma unroll
        for (int kc = 0; kc < 8; ++kc) {
            const int kf = kc*32 + grp*8;
            bf16x8 a[4], b[4];
            #pragma unroll
            for (int m=0;m<4;++m) {
                int row = w*64 + m*16 + colb;
                a[m] = __builtin_bit_cast(bf16x8, *(const uint4*)(Wb + (size_t)row*256 + kf));
            }
            #pragma unroll
            for (int n=0;n<4;++n) {
                int ee = n*16 + colb;
                b[n] = __builtin_bit_cast(bf16x8,
                         *(const uint4*)&Vs[(unsigned)(ee*256 + kf) ^ (unsigned)((ee&7)<<3)]);
            }
            #pragma unroll
            for (int m=0;m<4;++m)
                #pragma unroll
                for (int n=0;n<4;++n)
                    acc[m][n] = __builtin_amdgcn_mfma_f32_16x16x32_bf16(a[m], b[n], acc[m][n], 0, 0, 0);
        }
        __syncthreads();   // Vs reads complete before next tile's ds_write

        const int x0 = t*64, rq = grp*4;
        #pragma unroll
        for (int n=0;n<4;++n) {
            int edge = x0 + n*16 + colb;
            if (edge < E) {
                #pragma unroll
                for (int m=0;m<4;++m) {
                    f32x4 v = acc[m][n];
                    int r0 = w*64 + m*16 + rq;
                    uint2 q;
                    q.x = f2bu(v[0]) | (f2bu(v[1]) << 16);
                    q.y = f2bu(v[2]) | (f2bu(v[3]) << 16);
                    *(uint2*)(ucm + (size_t)edge*256 + r0) = q;
                    ls  += (double)v[0] + (double)v[1] + (double)v[2] + (double)v[3];
                    ls2 += (double)v[0]*v[0] + (double)v[1]*v[1]
                         + (double)v[2]*v[2] + (double)v[3]*v[3];
                }
            }
        }
    }
    block_red2(ls, ls2, sredw, tx, redp, blockIdx.x);
}

// ============ MFMA GEMM1 node: u[N][256] = KN1[256x384] @ [ave; div; xn] =====
__launch_bounds__(256)
__global__ void mfma_mm1_node(const bf16* __restrict__ Wb,   // [256 o][384 k]
                              const float* __restrict__ si,  // [N][128] f32 cm
                              const float* __restrict__ sj,
                              const float* __restrict__ xn,  // [N][128] f32 cm
                              bf16* __restrict__ ucm,        // [N][256] bf16
                              int Nn, double* __restrict__ redp)
{
    __shared__ __align__(16) unsigned short Vs[64*384];
    __shared__ double sredw[8];
    const int tx = threadIdx.x;
    const int x0 = blockIdx.x * 64;
    const int e = tx >> 2, q4 = tx & 3;
    const int node = x0 + e;
    const bool nv = node < Nn;
    const unsigned swz = (unsigned)((e & 7) << 3);

    #pragma unroll
    for (int p = 0; p < 4; ++p) {
        int k0 = q4*8 + p*32;
        uint4 va = make_uint4(0,0,0,0), vd = va;
        if (nv) {
            const float* ps = si + (size_t)node*128 + k0;
            const float* pt = sj + (size_t)node*128 + k0;
            float4 a0 = *(const float4*)ps, a1 = *(const float4*)(ps+4);
            float4 b0 = *(const float4*)pt, b1 = *(const float4*)(pt+4);
            float4 av0 = make_float4(0.5f*(a0.x+b0.x),0.5f*(a0.y+b0.y),
                                     0.5f*(a0.z+b0.z),0.5f*(a0.w+b0.w));
            float4 av1 = make_float4(0.5f*(a1.x+b1.x),0.5f*(a1.y+b1.y),
                                     0.5f*(a1.z+b1.z),0.5f*(a1.w+b1.w));
            float4 dv0 = make_float4(a0.x-b0.x,a0.y-b0.y,a0.z-b0.z,a0.w-b0.w);
            float4 dv1 = make_float4(a1.x-b1.x,a1.y-b1.y,a1.z-b1.z,a1.w-b1.w);
            va = pack8f(av0, av1);
            vd = pack8f(dv0, dv1);
        }
        *(uint4*)&Vs[(unsigned)(e*384 + k0) ^ swz] = va;
        *(uint4*)&Vs[(unsigned)(e*384 + 128 + k0) ^ swz] = vd;
    }
    #pragma unroll
    for (int p = 0; p < 4; ++p) {
        int k0 = q4*8 + p*32;
        uint4 v = make_uint4(0,0,0,0);
        if (nv) {
            const float* s = xn + (size_t)node*128 + k0;
            v = pack8f(*(const float4*)s, *(const float4*)(s + 4));
        }
        *(uint4*)&Vs[(unsigned)(e*384 + 256 + k0) ^ swz] = v;
    }
    __syncthreads();

    const int w = tx >> 6, l = tx & 63;
    const int colb = l & 15, grp = l >> 4;
    f32x4 acc[4][4];
    #pragma unroll
    for (int m=0;m<4;++m)
        #pragma unroll
        for (int n=0;n<4;++n) acc[m][n] = (f32x4){0.f,0.f,0.f,0.f};

    const bf16* wp = Wb + (size_t)(w*64 + colb)*384 + grp*8;
    #pragma unroll
    for (int kc = 0; kc < 12; ++kc) {
        const int kf = kc*32 + grp*8;
        bf16x8 a[4], b[4];
        #pragma unroll
        for (int m=0;m<4;++m)
            a[m] = __builtin_bit_cast(bf16x8, *(const uint4*)(wp + m*16*384 + kc*32));
        #pragma unroll
        for (int n=0;n<4;++n) {
            int ee = n*16 + colb;
            b[n] = __builtin_bit_cast(bf16x8,
                     *(const uint4*)&Vs[(unsigned)(ee*384 + kf) ^ (unsigned)((ee&7)<<3)]);
        }
        #pragma unroll
        for (int m=0;m<4;++m)
            #pragma unroll
            for (int n=0;n<4;++n)
                acc[m][n] = __builtin_amdgcn_mfma_f32_16x16x32_bf16(a[m], b[n], acc[m][n], 0, 0, 0);
    }

    double ls = 0.0, ls2 = 0.0;
    const int rq = grp*4;
    #pragma unroll
    for (int n=0;n<4;++n) {
        int nd = x0 + n*16 + colb;
        if (nd < Nn) {
            #pragma unroll
            for (int m=0;m<4;++m) {
                f32x4 v = acc[m][n];
                int r0 = w*64 + m*16 + rq;
                uint2 q;
                q.x = f2bu(v[0]) | (f2bu(v[1]) << 16);
                q.y = f2bu(v[2]) | (f2bu(v[3]) << 16);
                *(uint2*)(ucm + (size_t)nd*256 + r0) = q;
                ls  += (double)v[0] + (double)v[1] + (double)v[2] + (double)v[3];
                ls2 += (double)v[0]*v[0] + (double)v[1]*v[1]
                     + (double)v[2]*v[2] + (double)v[3]*v[3];
            }
        }
    }
    block_red2(ls, ls2, sredw, tx, redp, blockIdx.x);
}

// ==== persistent, pipelined MFMA GEMM2 (OC=128): y = W2 @ relu(LN(u)) ========
enum { E2_EDGE = 0, E2_NODE = 1, E2_XE0 = 2, E2_XN0 = 3 };

template<int IC, int EPI>
__launch_bounds__(256)
__global__ void mfma_mm2(const bf16* __restrict__ Wb2,   // [128 o][IC k]
                         const bf16* __restrict__ ucm,   // [n][IC] bf16
                         const float* __restrict__ ln,
                         float* __restrict__ dst,        // xe or xn, [n][128] f32 cm
                         bf16* __restrict__ yv,          // y [E][128] bf16 (EDGE)
                         bf16* __restrict__ shadow,      // bf16 copy of dst
                         int n, int ntiles)
{
    __shared__ __align__(16) unsigned short Vs[64*IC];
    const int tx = threadIdx.x;
    const int e = tx >> 2, q4 = tx & 3;
    const unsigned swz = (unsigned)((e & 7) << 3);
    const int w = tx >> 6, l = tx & 63;
    const int colb = l & 15, grp = l >> 4;
    const float mean = ln[0], rstd = ln[1];

    uint4 ru[IC/32];
    #pragma unroll
    for (int p=0;p<IC/32;++p) ru[p] = make_uint4(0,0,0,0);

    auto issue = [&](int tt){
        int row = tt*64 + e;
        if (row < n) {
            #pragma unroll
            for (int p=0;p<IC/32;++p)
                ru[p] = *(const uint4*)(ucm + (size_t)row*IC + q4*8 + p*32);
        }
    };

    int t = blockIdx.x;
    if (t < ntiles) issue(t);

    for (; t < ntiles; t += gridDim.x) {
        #pragma unroll
        for (int p=0;p<IC/32;++p) {
            int k0 = q4*8 + p*32;
            *(uint4*)&Vs[(unsigned)(e*IC + k0) ^ swz] = lnrelu_pack(ru[p], mean, rstd);
        }
        int tn = t + gridDim.x;
        if (tn < ntiles) issue(tn);
        __syncthreads();

        f32x4 acc[2][4];
        #pragma unroll
        for (int m=0;m<2;++m)
            #pragma unroll
            for (int nn=0;nn<4;++nn) acc[m][nn] = (f32x4){0.f,0.f,0.f,0.f};

        #pragma unroll
        for (int kc = 0; kc < IC/32; ++kc) {
            const int kf = kc*32 + grp*8;
            bf16x8 a[2], b[4];
            #pragma unroll
            for (int m=0;m<2;++m) {
                int rr = w*32 + m*16 + colb;
                a[m] = __builtin_bit_cast(bf16x8, *(const uint4*)(Wb2 + (size_t)rr*IC + kf));
            }
            #pragma unroll
            for (int nn=0;nn<4;++nn) {
                int ee = nn*16 + colb;
                b[nn] = __builtin_bit_cast(bf16x8,
                         *(const uint4*)&Vs[(unsigned)(ee*IC + kf) ^ (unsigned)((ee&7)<<3)]);
            }
            #pragma unroll
            for (int m=0;m<2;++m)
                #pragma unroll
                for (int nn=0;nn<4;++nn)
                    acc[m][nn] = __builtin_amdgcn_mfma_f32_16x16x32_bf16(a[m], b[nn], acc[m][nn], 0, 0, 0);
        }
        __syncthreads();   // Vs reads complete

        const int x0 = t*64, rq = grp*4;
        #pragma unroll
        for (int nn=0;nn<4;++nn) {
            int x = x0 + nn*16 + colb;
            if (x < n) {
                #pragma unroll
                for (int m=0;m<2;++m) {
                    f32x4 v = acc[m][nn];
                    int r0 = w*32 + m*16 + rq;
                    if constexpr (EPI == E2_EDGE) {
                        uint2 q;
                        q.x = f2bu(v[0]) | (f2bu(v[1]) << 16);
                        q.y = f2bu(v[2]) | (f2bu(v[3]) << 16);
                        *(uint2*)(yv + (size_t)x*128 + r0) = q;
                        float* px = dst + (size_t)x*128 + r0;
                        float4 o = *(float4*)px;
                        o.x += HSTEP*v[0]; o.y += HSTEP*v[1];
                        o.z += HSTEP*v[2]; o.w += HSTEP*v[3];
                        *(float4*)px = o;
                        uint2 sq;
                        sq.x = f2bu(o.x) | (f2bu(o.y) << 16);
                        sq.y = f2bu(o.z) | (f2bu(o.w) << 16);
                        *(uint2*)(shadow + (size_t)x*128 + r0) = sq;
                    } else if constexpr (EPI == E2_XE0) {
                        *(float4*)(dst + (size_t)x*128 + r0) =
                            make_float4(v[0], v[1], v[2], v[3]);
                        uint2 sq;
                        sq.x = f2bu(v[0]) | (f2bu(v[1]) << 16);
                        sq.y = f2bu(v[2]) | (f2bu(v[3]) << 16);
                        *(uint2*)(shadow + (size_t)x*128 + r0) = sq;
                    } else if constexpr (EPI == E2_NODE) {
                        float* px = dst + (size_t)x*128 + r0;
                        float4 o = *(float4*)px;
                        o.x += HSTEP*v[0]; o.y += HSTEP*v[1];
                        o.z += HSTEP*v[2]; o.w += HSTEP*v[3];
                        *(float4*)px = o;
                        uint2 q;
                        q.x = f2bu(o.x) | (f2bu(o.y) << 16);
                        q.y = f2bu(o.z) | (f2bu(o.w) << 16);
                        *(uint2*)(shadow + (size_t)x*128 + r0) = q;
                    } else {  // E2_XN0
                        *(float4*)(dst + (size_t)x*128 + r0) =
                            make_float4(v[0], v[1], v[2], v[3]);
                        uint2 q;
                        q.x = f2bu(v[0]) | (f2bu(v[1]) << 16);
                        q.y = f2bu(v[2]) | (f2bu(v[3]) << 16);
                        *(uint2*)(shadow + (size_t)x*128 + r0) = q;
                    }
                }
            }
        }
    }
}

// ---------------- opening GEMM1 (VALU, IC=32): u[n][128] bf16 cm --------------
__launch_bounds__(256)
__global__ void mm1_open(const float* __restrict__ Wt,   // [32][128]
                         const float* __restrict__ xin,  // [32][n] f32 rm
                         bf16* __restrict__ ucm,         // [n][128] bf16
                         int n, double* __restrict__ redp)
{
    __shared__ float lv[32][64];
    __shared__ double sredw[8];
    const int tx = threadIdx.x;
    const int tr = tx & 31, tc = tx >> 5;
    const int x0 = blockIdx.x * 64;

    float acc[4][8];
    #pragma unroll
    for (int ri=0; ri<4; ++ri)
        #pragma unroll
        for (int ei=0; ei<8; ++ei) acc[ri][ei] = 0.f;

    #pragma unroll
    for (int k=0; k<2; ++k) {
        int id = k*256 + tx;
        int xq = id & 15, cc = id >> 4;
        int x = x0 + xq*4;
        const float* p = xin + (size_t)cc*n + x;
        float4 q;
        if (x + 3 < n) q = *(const float4*)p;
        else {
            q.x = (x  <n)?p[0]:0.f; q.y = (x+1<n)?p[1]:0.f;
            q.z = (x+2<n)?p[2]:0.f; q.w = (x+3<n)?p[3]:0.f;
        }
        *(float4*)&lv[cc][xq*4] = q;
    }
    __syncthreads();
    for (int cc=0; cc<32; ++cc) {
        const float* wrow = Wt + cc*128 + tr*4;
        float w[4] = {wrow[0], wrow[1], wrow[2], wrow[3]};
        float vv[8];
        #pragma unroll
        for (int ei=0; ei<8; ++ei) vv[ei] = lv[cc][tc*8+ei];
        #pragma unroll
        for (int ri=0; ri<4; ++ri)
            #pragma unroll
            for (int ei=0; ei<8; ++ei)
                acc[ri][ei] = fmaf(w[ri], vv[ei], acc[ri][ei]);
    }

    double ls = 0.0, ls2 = 0.0;
    #pragma unroll
    for (int ei=0; ei<8; ++ei) {
        int x = x0 + tc*8 + ei;
        if (x < n) {
            uint2 bq;
            bq.x = f2bu(acc[0][ei]) | (f2bu(acc[1][ei]) << 16);
            bq.y = f2bu(acc[2][ei]) | (f2bu(acc[3][ei]) << 16);
            *(uint2*)(ucm + (size_t)x*128 + tr*4) = bq;
            #pragma unroll
            for (int ri=0; ri<4; ++ri) {
                double y = acc[ri][ei]; ls += y; ls2 += y*y;
            }
        }
    }
    block_red2(ls, ls2, sredw, tx, redp, blockIdx.x);
}

// ---------------- final: out[64][N] = KNout @ xn (VALU) ----------------
__launch_bounds__(256)
__global__ void final_out(const float* __restrict__ Wt,   // [128 c][64 o]
                          const float* __restrict__ xncm, // [N][128] f32
                          float* __restrict__ out, int n)
{
    __shared__ float lv[32][64];
    const int tx = threadIdx.x;
    const int tr = tx & 31, tc = tx >> 5;
    const int x0 = blockIdx.x * 64;

    float acc[2][8];
    #pragma unroll
    for (int ri=0; ri<2; ++ri)
        #pragma unroll
        for (int ei=0; ei<8; ++ei) acc[ri][ei] = 0.f;

    for (int c0 = 0; c0 < 128; c0 += 32) {
        #pragma unroll
        for (int k=0; k<2; ++k) {
            int id = k*256 + tx;
            int xx = id & 63, cg = id >> 6;
            int x = x0 + xx;
            float4 q;
            if (x < n) q = *(const float4*)(xncm + (size_t)x*128 + c0 + cg*4);
            else { q.x=q.y=q.z=q.w=0.f; }
            lv[cg*4+0][xx]=q.x; lv[cg*4+1][xx]=q.y;
            lv[cg*4+2][xx]=q.z; lv[cg*4+3][xx]=q.w;
        }
        __syncthreads();
        for (int cc=0; cc<32; ++cc) {
            const float* wrow = Wt + (c0+cc)*64 + tr*2;
            float w0 = wrow[0], w1 = wrow[1];
            float vv[8];
            #pragma unroll
            for (int ei=0; ei<8; ++ei) vv[ei] = lv[cc][tc*8+ei];
            #pragma unroll
            for (int ei=0; ei<8; ++ei) {
                acc[0][ei] = fmaf(w0, vv[ei], acc[0][ei]);
                acc[1][ei] = fmaf(w1, vv[ei], acc[1][ei]);
            }
        }
        __syncthreads();
    }

    const bool full = (x0 + 64 <= n);
    #pragma unroll
    for (int ri=0; ri<2; ++ri) {
        int r = tr*2 + ri;
        if (full) {
            store8(out + (size_t)r*n + x0 + tc*8, acc[ri]);
        } else {
            #pragma unroll
            for (int ei=0; ei<8; ++ei) {
                int x = x0 + tc*8 + ei;
                if (x < n) out[(size_t)r*n + x] = acc[ri][ei];
            }
        }
    }
}

// ---------------- xe col-major -> row-major f32 output ----------------
__launch_bounds__(256)
__global__ void xe_transpose(const float* __restrict__ xe, float* __restrict__ out, int E)
{
    __shared__ float T[128][65];
    const int tx = threadIdx.x;
    const int x0 = blockIdx.x * 64;
    const int es = tx & 63, cg = tx >> 6;
    #pragma unroll
    for (int p = 0; p < 8; ++p) {
        int c = cg*4 + p*16;
        if (x0 + es < E) {
            float4 v = *(const float4*)(xe + (size_t)(x0+es)*128 + c);
            T[c+0][es] = v.x; T[c+1][es] = v.y; T[c+2][es] = v.z; T[c+3][es] = v.w;
        }
    }
    __syncthreads();
    const int c2 = tx >> 1, eo = (tx & 1)*32;
    if (x0 + 64 <= E) {
        #pragma unroll
        for (int q = 0; q < 8; ++q) {
            float4 v = make_float4(T[c2][eo+q*4], T[c2][eo+q*4+1],
                                   T[c2][eo+q*4+2], T[c2][eo+q*4+3]);
            *(float4*)(out + (size_t)c2*E + x0 + eo + q*4) = v;
        }
    } else {
        for (int q = 0; q < 32; ++q) {
            int x = x0 + eo + q;
            if (x < E) out[(size_t)c2*E + x] = T[c2][eo+q];
        }
    }
}

extern "C" void kernel_launch(void* const* d_in, const int* in_sizes, int n_in,
                              void* d_out, int out_size, void* d_ws, size_t ws_size,
                              hipStream_t stream)
{
    const int N = in_sizes[0] / 32;          // 50000
    const int E = in_sizes[1] / 32;          // 500000
    const int NL = in_sizes[9] / (256*384);  // 4

    const float* xn_in = (const float*)d_in[0];
    const float* xe_in = (const float*)d_in[1];
    const int*   iInd  = (const int*)d_in[2];
    const int*   jInd  = (const int*)d_in[3];
    const float* K1N = (const float*)d_in[4];
    const float* K2N = (const float*)d_in[5];
    const float* K1E = (const float*)d_in[6];
    const float* K2E = (const float*)d_in[7];
    const float* KNo = (const float*)d_in[8];
    const float* KE1 = (const float*)d_in[9];
    const float* KE2 = (const float*)d_in[10];
    const float* KN1 = (const float*)d_in[11];
    const float* KN2 = (const float*)d_in[12];

    char* base = (char*)d_ws;
    size_t off = 0;
    auto carve = [&](size_t bytes)->void* {
        void* p = base + off; off += (bytes + 255) & ~(size_t)255; return p;
    };
    float* xn  = (float*)carve((size_t)128*N*sizeof(float));  // [N][128] cm
    float* xe  = (float*)carve((size_t)128*E*sizeof(float));  // [E][128] cm
    bf16*  xeb = (bf16*) carve((size_t)128*E*sizeof(bf16));   // xe bf16 shadow
    bf16*  u   = (bf16*) carve((size_t)256*E*sizeof(bf16));   // [n][IC] cm bf16
    bf16*  y   = (bf16*) carve((size_t)128*E*sizeof(bf16));   // [E][128] bf16
    float* si  = (float*)carve((size_t)128*N*sizeof(float));
    float* sj  = (float*)carve((size_t)128*N*sizeof(float));
    float* wtsf= (float*)carve((32*128*2 + 128*64)*sizeof(float));
    bf16*  Wb   = (bf16*)carve((size_t)256*256*sizeof(bf16)); // folded KE1
    bf16*  Wb2  = (bf16*)carve((size_t)128*256*sizeof(bf16)); // KE2
    bf16*  Wn1b = (bf16*)carve((size_t)256*384*sizeof(bf16)); // KN1
    bf16*  Wn2b = (bf16*)carve((size_t)128*256*sizeof(bf16)); // KN2
    bf16*  K2Nb = (bf16*)carve((size_t)128*128*sizeof(bf16));
    bf16*  K2Eb = (bf16*)carve((size_t)128*128*sizeof(bf16));
    bf16*  xnb  = (bf16*)carve((size_t)128*N*sizeof(bf16));   // xn shadow
    double* redp = (double*)carve(2*8192*sizeof(double));
    float* lnp = (float*)carve(256);
    int* cnt      = (int*)carve((size_t)N*sizeof(int));
    int* rowptr_i = (int*)carve((size_t)(N+1)*sizeof(int));
    int* rowptr_j = (int*)carve((size_t)(N+1)*sizeof(int));
    int* cur_i    = (int*)carve((size_t)N*sizeof(int));
    int* cur_j    = (int*)carve((size_t)N*sizeof(int));
    int* eadj_i   = (int*)carve((size_t)E*sizeof(int));
    int* eadj_j   = (int*)carve((size_t)E*sizeof(int));

    if (ws_size < off) return;

    float* K1Nt = wtsf;                // [32][128]
    float* K1Et = K1Nt + 32*128;       // [32][128]
    float* KNoT = K1Et + 32*128;       // [128][64]

    wt_transpose<<<dim3((128*32 +255)/256),dim3(256),0,stream>>>(K1N, K1Nt, 128, 32);
    wt_transpose<<<dim3((128*32 +255)/256),dim3(256),0,stream>>>(K1E, K1Et, 128, 32);
    wt_transpose<<<dim3((64*128 +255)/256),dim3(256),0,stream>>>(KNo, KNoT, 64, 128);
    wt_cast_bf<<<dim3(64),dim3(256),0,stream>>>(K2N, K2Nb, 128*128);
    wt_cast_bf<<<dim3(64),dim3(256),0,stream>>>(K2E, K2Eb, 128*128);

    const int gN = (N + 63)/64, gE = (E + 63)/64;
    const int gEb = (E + 255)/256;
    const int PE = (gE < 2048) ? gE : 2048;     // persistent grid for E-kernels
    const int PN = (gN < 2048) ? gN : 2048;

    // CSR build once
    (void)hipMemsetAsync(cnt, 0, (size_t)N*sizeof(int), stream);
    csr_hist<<<gEb,256,0,stream>>>(iInd, cnt, E);
    csr_scan<<<1,256,0,stream>>>(cnt, rowptr_i, cur_i, N);
    csr_fill<<<gEb,256,0,stream>>>(iInd, cur_i, eadj_i, E);
    (void)hipMemsetAsync(cnt, 0, (size_t)N*sizeof(int), stream);
    csr_hist<<<gEb,256,0,stream>>>(jInd, cnt, E);
    csr_scan<<<1,256,0,stream>>>(cnt, rowptr_j, cur_j, N);
    csr_fill<<<gEb,256,0,stream>>>(jInd, cur_j, eadj_j, E);

    // ---- opening: nodes ----
    mm1_open<<<gN,256,0,stream>>>(K1Nt, xn_in, u, N, redp);
    ln_reduce<<<1,256,0,stream>>>(redp, gN, lnp, 128.0*N);
    mfma_mm2<128,E2_XN0><<<PN,256,0,stream>>>(K2Nb, u, lnp, xn, nullptr, xnb, N, gN);

    // ---- opening: edges ----
    mm1_open<<<gE,256,0,stream>>>(K1Et, xe_in, u, E, redp);
    ln_reduce<<<1,256,0,stream>>>(redp, gE, lnp, 128.0*E);
    mfma_mm2<128,E2_XE0><<<PE,256,0,stream>>>(K2Eb, u, lnp, xe, nullptr, xeb, E, gE);

    for (int l = 0; l < NL; ++l) {
        wt_ke1_bf<<<dim3(256),dim3(256),0,stream>>>(KE1 + (size_t)l*256*384, Wb);
        wt_cast_bf<<<dim3(128),dim3(256),0,stream>>>(KE2 + (size_t)l*128*256, Wb2, 128*256);
        wt_cast_bf<<<dim3(384),dim3(256),0,stream>>>(KN1 + (size_t)l*256*384, Wn1b, 256*384);
        wt_cast_bf<<<dim3(128),dim3(256),0,stream>>>(KN2 + (size_t)l*128*256, Wn2b, 128*256);

        // edge double_layer (MFMA, persistent pipelined)
        mfma_mm1_edge<<<PE,256,0,stream>>>(Wb, xnb, xeb, iInd, u, E, gE, redp);
        ln_reduce<<<1,256,0,stream>>>(redp, PE, lnp, 256.0*E);
        mfma_mm2<256,E2_EDGE><<<PE,256,0,stream>>>(Wb2, u, lnp, xe, y, xeb, E, gE);
        gather_nodes<<<(N+3)/4,256,0,stream>>>(y, rowptr_i, eadj_i, si, N);
        gather_nodes<<<(N+3)/4,256,0,stream>>>(y, rowptr_j, eadj_j, sj, N);

        // node double_layer (MFMA)
        mfma_mm1_node<<<gN,256,0,stream>>>(Wn1b, si, sj, xn, u, N, redp);
        ln_reduce<<<1,256,0,stream>>>(redp, gN, lnp, 256.0*N);
        mfma_mm2<256,E2_NODE><<<PN,256,0,stream>>>(Wn2b, u, lnp, xn, nullptr, xnb, N, gN);
    }

    // ---- final ----
    final_out<<<gN,256,0,stream>>>(KNoT, xn, (float*)d_out, N);
    xe_transpose<<<gE,256,0,stream>>>(xe, (float*)d_out + (size_t)64*N, E);
}